// Round 1
// baseline (305.919 us; speedup 1.0000x reference)
//
#include <hip/hip_runtime.h>
#include <hip/hip_bf16.h>
#include <stdint.h>
#include <stddef.h>

#define B_ 2
#define T_ 2048
#define C_ 1024
#define H_ 16
#define D_ 64
#define M_ (B_*T_)   // 4096

typedef __attribute__((ext_vector_type(8))) short short8;
typedef __attribute__((ext_vector_type(4))) float f32x4;

__device__ __forceinline__ unsigned short f2bf(float f) {
    unsigned u = __float_as_uint(f);
    unsigned r = 0x7FFFu + ((u >> 16) & 1u);
    return (unsigned short)((u + r) >> 16);
}

__device__ __forceinline__ void gload16(const void* g, void* l) {
    __builtin_amdgcn_global_load_lds(
        (__attribute__((address_space(1))) void*)g,
        (__attribute__((address_space(3))) void*)l,
        16, 0, 0);
}

// ---------------- fp32 -> bf16 conversion ----------------
__global__ void cvt_bf16(const float* __restrict__ in,
                         unsigned short* __restrict__ out, int n) {
    int idx = (blockIdx.x * blockDim.x + threadIdx.x) * 4;
    if (idx >= n) return;
    float4 v = *reinterpret_cast<const float4*>(in + idx);
    ushort4 o;
    o.x = f2bf(v.x); o.y = f2bf(v.y); o.z = f2bf(v.z); o.w = f2bf(v.w);
    *reinterpret_cast<ushort4*>(out + idx) = o;
}

// ---------------- fused QKV projection GEMM ----------------
// A: x bf16 [M_][C_], W*: bf16 [C_][C_] (row n holds W[n][k]) -> out = A*W^T + b
// which 0 -> K  [B,H,T,D], which 1 -> Q [B,H,T,D], which 2 -> V^T [B,H,D,T]
__global__ __launch_bounds__(256) void gemm_qkv(
    const unsigned short* __restrict__ A,
    const unsigned short* __restrict__ W0,
    const unsigned short* __restrict__ W1,
    const unsigned short* __restrict__ W2,
    const float* __restrict__ b0,
    const float* __restrict__ b1,
    const float* __restrict__ b2,
    unsigned short* __restrict__ o0,   // k
    unsigned short* __restrict__ o1,   // q
    unsigned short* __restrict__ o2)   // vt
{
    __shared__ unsigned short As[128*32];
    __shared__ unsigned short Bs[128*32];
    int which = blockIdx.x >> 8;
    int bx = blockIdx.x & 255;
    int bm = bx >> 3, bn = bx & 7;
    const unsigned short* W = (which==0) ? W0 : ((which==1) ? W1 : W2);
    const float* bias = (which==0) ? b0 : ((which==1) ? b1 : b2);

    int tid = threadIdx.x;
    int lane = tid & 63;
    int fr = lane & 15, fq = lane >> 4;
    int wid = tid >> 6;
    int wr = wid >> 1, wc = wid & 1;

    int srow = tid >> 2;            // 0..63
    int scol = (tid & 3) << 3;      // 0,8,16,24
    const unsigned short* Ab = A + (size_t)(bm*128 + srow) * C_ + scol;
    const unsigned short* Wb = W + (size_t)(bn*128 + srow) * C_ + scol;

    f32x4 acc[4][4] = {};

    for (int kt = 0; kt < C_/32; ++kt) {
        int ko = kt*32;
        gload16(Ab + ko,            &As[tid*8]);
        gload16(Ab + 64*C_ + ko,    &As[2048 + tid*8]);
        gload16(Wb + ko,            &Bs[tid*8]);
        gload16(Wb + 64*C_ + ko,    &Bs[2048 + tid*8]);
        __syncthreads();
        short8 af[4], bfr[4];
        #pragma unroll
        for (int i = 0; i < 4; ++i) {
            af[i]  = *reinterpret_cast<const short8*>(&As[(wr*64 + i*16 + fr)*32 + fq*8]);
            bfr[i] = *reinterpret_cast<const short8*>(&Bs[(wc*64 + i*16 + fr)*32 + fq*8]);
        }
        #pragma unroll
        for (int i = 0; i < 4; ++i)
            #pragma unroll
            for (int j = 0; j < 4; ++j)
                acc[i][j] = __builtin_amdgcn_mfma_f32_16x16x32_bf16(af[i], bfr[j], acc[i][j], 0, 0, 0);
        __syncthreads();
    }

    int mbase = bm*128 + wr*64;
    int nbase = bn*128 + wc*64;
    #pragma unroll
    for (int j = 0; j < 4; ++j) {
        int col = nbase + j*16 + fr;
        float bv = bias[col];
        int h = col >> 6, d = col & 63;
        #pragma unroll
        for (int i = 0; i < 4; ++i) {
            int r0 = mbase + i*16 + fq*4;
            #pragma unroll
            for (int r = 0; r < 4; ++r) {
                float v = acc[i][j][r] + bv;
                int m = r0 + r;
                int b = m >> 11, t = m & (T_-1);
                unsigned short hv = f2bf(v);
                if (which == 2)
                    o2[((size_t)(b*H_ + h)*D_ + d)*T_ + t] = hv;
                else {
                    unsigned short* o = (which==0) ? o0 : o1;
                    o[((size_t)(b*H_ + h)*T_ + t)*D_ + d] = hv;
                }
            }
        }
    }
}

// ---------------- output projection GEMM ----------------
__global__ __launch_bounds__(256) void gemm_out(
    const unsigned short* __restrict__ A,   // y bf16 [M_][C_]
    const unsigned short* __restrict__ W,   // Wo bf16 [C_][C_]
    const float* __restrict__ bias,
    float* __restrict__ out)
{
    __shared__ unsigned short As[128*32];
    __shared__ unsigned short Bs[128*32];
    int bx = blockIdx.x;
    int bm = bx >> 3, bn = bx & 7;

    int tid = threadIdx.x;
    int lane = tid & 63;
    int fr = lane & 15, fq = lane >> 4;
    int wid = tid >> 6;
    int wr = wid >> 1, wc = wid & 1;

    int srow = tid >> 2;
    int scol = (tid & 3) << 3;
    const unsigned short* Ab = A + (size_t)(bm*128 + srow) * C_ + scol;
    const unsigned short* Wb = W + (size_t)(bn*128 + srow) * C_ + scol;

    f32x4 acc[4][4] = {};

    for (int kt = 0; kt < C_/32; ++kt) {
        int ko = kt*32;
        gload16(Ab + ko,            &As[tid*8]);
        gload16(Ab + 64*C_ + ko,    &As[2048 + tid*8]);
        gload16(Wb + ko,            &Bs[tid*8]);
        gload16(Wb + 64*C_ + ko,    &Bs[2048 + tid*8]);
        __syncthreads();
        short8 af[4], bfr[4];
        #pragma unroll
        for (int i = 0; i < 4; ++i) {
            af[i]  = *reinterpret_cast<const short8*>(&As[(wr*64 + i*16 + fr)*32 + fq*8]);
            bfr[i] = *reinterpret_cast<const short8*>(&Bs[(wc*64 + i*16 + fr)*32 + fq*8]);
        }
        #pragma unroll
        for (int i = 0; i < 4; ++i)
            #pragma unroll
            for (int j = 0; j < 4; ++j)
                acc[i][j] = __builtin_amdgcn_mfma_f32_16x16x32_bf16(af[i], bfr[j], acc[i][j], 0, 0, 0);
        __syncthreads();
    }

    int mbase = bm*128 + wr*64;
    int nbase = bn*128 + wc*64;
    #pragma unroll
    for (int j = 0; j < 4; ++j) {
        int col = nbase + j*16 + fr;
        float bv = bias[col];
        #pragma unroll
        for (int i = 0; i < 4; ++i) {
            int r0 = mbase + i*16 + fq*4;
            #pragma unroll
            for (int r = 0; r < 4; ++r)
                out[(size_t)(r0 + r)*C_ + col] = acc[i][j][r] + bv;
        }
    }
}

// ---------------- flash attention (causal) ----------------
// q,k: [B*H][T][D] bf16 ; vt: [B*H][D][T] bf16 ; y: [B*T][C] bf16
__global__ __launch_bounds__(256) void flash_attn(
    const unsigned short* __restrict__ q,
    const unsigned short* __restrict__ k,
    const unsigned short* __restrict__ vt,
    unsigned short* __restrict__ y)
{
    __shared__ unsigned short Pl[4][16*64];   // per-wave P buffer (2KB each)
    int tid = threadIdx.x, lane = tid & 63, wid = tid >> 6;
    int gw = blockIdx.x * 4 + wid;            // 0..4095
    int qt = 127 - (gw & 127);                // heavy tiles first
    int bh = gw >> 7;                         // 0..31

    const unsigned short* qp = q  + ((size_t)bh*T_ + qt*16) * D_;
    const unsigned short* kp = k  + (size_t)bh*T_*D_;
    const unsigned short* vp = vt + (size_t)bh*D_*T_;
    int fr = lane & 15, fq = lane >> 4;

    short8 aq0 = *reinterpret_cast<const short8*>(qp + fr*D_ + fq*8);
    short8 aq1 = *reinterpret_cast<const short8*>(qp + fr*D_ + 32 + fq*8);

    f32x4 o[4] = {};
    float m_[4], l_[4];
    #pragma unroll
    for (int r = 0; r < 4; ++r) { m_[r] = -1e30f; l_[r] = 0.f; }

    unsigned short* P = Pl[wid];
    int nsteps = ((qt*16 + 15) >> 6) + 1;
    const float scale = 0.03125f;   // 1/sqrt(1024)

    for (int s = 0; s < nsteps; ++s) {
        int kv0 = s * 64;
        f32x4 sc[4];
        #pragma unroll
        for (int ct = 0; ct < 4; ++ct) {
            const unsigned short* kr = kp + (size_t)(kv0 + ct*16 + fr) * D_ + fq*8;
            short8 kb0 = *reinterpret_cast<const short8*>(kr);
            short8 kb1 = *reinterpret_cast<const short8*>(kr + 32);
            f32x4 z = {};
            z = __builtin_amdgcn_mfma_f32_16x16x32_bf16(aq0, kb0, z, 0, 0, 0);
            z = __builtin_amdgcn_mfma_f32_16x16x32_bf16(aq1, kb1, z, 0, 0, 0);
            sc[ct] = z;
        }
        // scale + causal mask
        #pragma unroll
        for (int ct = 0; ct < 4; ++ct) {
            int col = kv0 + ct*16 + fr;
            #pragma unroll
            for (int r = 0; r < 4; ++r) {
                float v = sc[ct][r] * scale;
                int row = qt*16 + fq*4 + r;
                sc[ct][r] = (col > row) ? -1e30f : v;
            }
        }
        // row max (across cts then across the 16 lanes of the group)
        float pm[4];
        #pragma unroll
        for (int r = 0; r < 4; ++r)
            pm[r] = fmaxf(fmaxf(sc[0][r], sc[1][r]), fmaxf(sc[2][r], sc[3][r]));
        #pragma unroll
        for (int r = 0; r < 4; ++r) {
            float v = pm[r];
            v = fmaxf(v, __shfl_xor(v, 1));
            v = fmaxf(v, __shfl_xor(v, 2));
            v = fmaxf(v, __shfl_xor(v, 4));
            v = fmaxf(v, __shfl_xor(v, 8));
            pm[r] = v;
        }
        float alpha[4], rs[4];
        #pragma unroll
        for (int r = 0; r < 4; ++r) {
            float mn = fmaxf(m_[r], pm[r]);
            alpha[r] = __expf(m_[r] - mn);
            m_[r] = mn;
            rs[r] = 0.f;
        }
        // P = exp(s - m) -> LDS (bf16), accumulate row sums
        #pragma unroll
        for (int ct = 0; ct < 4; ++ct) {
            #pragma unroll
            for (int r = 0; r < 4; ++r) {
                float p = __expf(sc[ct][r] - m_[r]);
                rs[r] += p;
                P[(fq*4 + r)*64 + ct*16 + fr] = f2bf(p);
            }
        }
        #pragma unroll
        for (int r = 0; r < 4; ++r) {
            float v = rs[r];
            v += __shfl_xor(v, 1);
            v += __shfl_xor(v, 2);
            v += __shfl_xor(v, 4);
            v += __shfl_xor(v, 8);
            l_[r] = l_[r] * alpha[r] + v;
        }
        #pragma unroll
        for (int dt = 0; dt < 4; ++dt)
            #pragma unroll
            for (int r = 0; r < 4; ++r)
                o[dt][r] *= alpha[r];
        // P·V
        short8 ap0 = *reinterpret_cast<const short8*>(&P[fr*64 + fq*8]);
        short8 ap1 = *reinterpret_cast<const short8*>(&P[fr*64 + 32 + fq*8]);
        #pragma unroll
        for (int dt = 0; dt < 4; ++dt) {
            const unsigned short* vr = vp + (size_t)(dt*16 + fr)*T_ + kv0 + fq*8;
            short8 vb0 = *reinterpret_cast<const short8*>(vr);
            short8 vb1 = *reinterpret_cast<const short8*>(vr + 32);
            o[dt] = __builtin_amdgcn_mfma_f32_16x16x32_bf16(ap0, vb0, o[dt], 0, 0, 0);
            o[dt] = __builtin_amdgcn_mfma_f32_16x16x32_bf16(ap1, vb1, o[dt], 0, 0, 0);
        }
    }

    int b = bh >> 4, h = bh & 15;
    #pragma unroll
    for (int r = 0; r < 4; ++r) {
        int trow = qt*16 + fq*4 + r;
        size_t rowbase = ((size_t)(b*T_ + trow))*C_ + h*64;
        float inv = 1.0f / l_[r];
        #pragma unroll
        for (int dt = 0; dt < 4; ++dt)
            y[rowbase + dt*16 + fr] = f2bf(o[dt][r] * inv);
    }
}

extern "C" void kernel_launch(void* const* d_in, const int* in_sizes, int n_in,
                              void* d_out, int out_size, void* d_ws, size_t ws_size,
                              hipStream_t stream) {
    const float* x  = (const float*)d_in[0];
    const float* Wk = (const float*)d_in[1];
    const float* bk = (const float*)d_in[2];
    const float* Wq = (const float*)d_in[3];
    const float* bq = (const float*)d_in[4];
    const float* Wv = (const float*)d_in[5];
    const float* bv = (const float*)d_in[6];
    const float* Wo = (const float*)d_in[7];
    const float* bo = (const float*)d_in[8];
    float* out = (float*)d_out;

    char* ws = (char*)d_ws;
    unsigned short* xb  = (unsigned short*)(ws);                    // 8MB
    unsigned short* wkb = (unsigned short*)(ws + ((size_t)8  << 20));
    unsigned short* wqb = (unsigned short*)(ws + ((size_t)10 << 20));
    unsigned short* wvb = (unsigned short*)(ws + ((size_t)12 << 20));
    unsigned short* wob = (unsigned short*)(ws + ((size_t)14 << 20));
    unsigned short* qb  = (unsigned short*)(ws + ((size_t)16 << 20)); // [B,H,T,D]
    unsigned short* kb  = (unsigned short*)(ws + ((size_t)24 << 20)); // [B,H,T,D]
    unsigned short* vtb = (unsigned short*)(ws + ((size_t)32 << 20)); // [B,H,D,T]
    unsigned short* yb  = (unsigned short*)(ws + ((size_t)40 << 20)); // [B*T,C]

    const int nx = B_*T_*C_;   // 4M
    const int nw = C_*C_;      // 1M

    cvt_bf16<<<dim3(nx/4/256), dim3(256), 0, stream>>>(x,  xb,  nx);
    cvt_bf16<<<dim3(nw/4/256), dim3(256), 0, stream>>>(Wk, wkb, nw);
    cvt_bf16<<<dim3(nw/4/256), dim3(256), 0, stream>>>(Wq, wqb, nw);
    cvt_bf16<<<dim3(nw/4/256), dim3(256), 0, stream>>>(Wv, wvb, nw);
    cvt_bf16<<<dim3(nw/4/256), dim3(256), 0, stream>>>(Wo, wob, nw);

    gemm_qkv<<<dim3(768), dim3(256), 0, stream>>>(xb, wkb, wqb, wvb, bk, bq, bv, kb, qb, vtb);

    flash_attn<<<dim3(1024), dim3(256), 0, stream>>>(qb, kb, vtb, yb);

    gemm_out<<<dim3(256), dim3(256), 0, stream>>>(yb, wob, bo, out);
}

// Round 2
// 169.433 us; speedup vs baseline: 1.8055x; 1.8055x over previous
//
#include <hip/hip_runtime.h>
#include <hip/hip_bf16.h>
#include <stdint.h>
#include <stddef.h>

#define B_ 2
#define T_ 2048
#define C_ 1024
#define H_ 16
#define D_ 64
#define M_ (B_*T_)   // 4096

typedef __attribute__((ext_vector_type(8))) short short8;
typedef __attribute__((ext_vector_type(4))) float f32x4;
typedef __attribute__((ext_vector_type(16))) float f32x16;
typedef __attribute__((ext_vector_type(4))) unsigned int u32x4;

__device__ __forceinline__ unsigned short f2bf(float f) {
    unsigned u = __float_as_uint(f);
    unsigned r = 0x7FFFu + ((u >> 16) & 1u);
    return (unsigned short)((u + r) >> 16);
}

__device__ __forceinline__ unsigned cvtpk_bf16(float lo, float hi) {
    unsigned r;
    asm("v_cvt_pk_bf16_f32 %0, %1, %2" : "=v"(r) : "v"(lo), "v"(hi));
    return r;
}

__device__ __forceinline__ void gload16(const void* g, void* l) {
    __builtin_amdgcn_global_load_lds(
        (__attribute__((address_space(1))) void*)g,
        (__attribute__((address_space(3))) void*)l,
        16, 0, 0);
}

// ---------------- fp32 -> bf16 conversion ----------------
__global__ void cvt_bf16(const float* __restrict__ in,
                         unsigned short* __restrict__ out, int n) {
    int idx = (blockIdx.x * blockDim.x + threadIdx.x) * 4;
    if (idx >= n) return;
    float4 v = *reinterpret_cast<const float4*>(in + idx);
    ushort4 o;
    o.x = f2bf(v.x); o.y = f2bf(v.y); o.z = f2bf(v.z); o.w = f2bf(v.w);
    *reinterpret_cast<ushort4*>(out + idx) = o;
}

// 4 weight tensors in one launch (blockIdx.y selects tensor)
__global__ void cvt_bf16_w4(const float* __restrict__ a, const float* __restrict__ b,
                            const float* __restrict__ c, const float* __restrict__ d,
                            unsigned short* __restrict__ oa, unsigned short* __restrict__ ob,
                            unsigned short* __restrict__ oc, unsigned short* __restrict__ od,
                            int n) {
    int idx = (blockIdx.x * blockDim.x + threadIdx.x) * 4;
    if (idx >= n) return;
    const float* in = (blockIdx.y == 0) ? a : (blockIdx.y == 1) ? b : (blockIdx.y == 2) ? c : d;
    unsigned short* out = (blockIdx.y == 0) ? oa : (blockIdx.y == 1) ? ob : (blockIdx.y == 2) ? oc : od;
    float4 v = *reinterpret_cast<const float4*>(in + idx);
    ushort4 o;
    o.x = f2bf(v.x); o.y = f2bf(v.y); o.z = f2bf(v.z); o.w = f2bf(v.w);
    *reinterpret_cast<ushort4*>(out + idx) = o;
}

// ---------------- fused QKV projection GEMM ----------------
// which 0 -> K [B,H,T,D], which 1 -> Q*scale [B,H,T,D], which 2 -> V^T [B,H,D,T]
__global__ __launch_bounds__(256) void gemm_qkv(
    const unsigned short* __restrict__ A,
    const unsigned short* __restrict__ W0,
    const unsigned short* __restrict__ W1,
    const unsigned short* __restrict__ W2,
    const float* __restrict__ b0,
    const float* __restrict__ b1,
    const float* __restrict__ b2,
    unsigned short* __restrict__ o0,   // k
    unsigned short* __restrict__ o1,   // q (pre-scaled by 1/32)
    unsigned short* __restrict__ o2)   // vt
{
    __shared__ unsigned short As[128*32];
    __shared__ unsigned short Bs[128*32];
    int which = blockIdx.x >> 8;
    int bx = blockIdx.x & 255;
    int bm = bx >> 3, bn = bx & 7;
    const unsigned short* W = (which==0) ? W0 : ((which==1) ? W1 : W2);
    const float* bias = (which==0) ? b0 : ((which==1) ? b1 : b2);

    int tid = threadIdx.x;
    int lane = tid & 63;
    int fr = lane & 15, fq = lane >> 4;
    int wid = tid >> 6;
    int wr = wid >> 1, wc = wid & 1;

    int srow = tid >> 2;            // 0..63
    int scol = (tid & 3) << 3;      // 0,8,16,24
    const unsigned short* Ab = A + (size_t)(bm*128 + srow) * C_ + scol;
    const unsigned short* Wb = W + (size_t)(bn*128 + srow) * C_ + scol;

    f32x4 acc[4][4] = {};

    for (int kt = 0; kt < C_/32; ++kt) {
        int ko = kt*32;
        gload16(Ab + ko,            &As[tid*8]);
        gload16(Ab + 64*C_ + ko,    &As[2048 + tid*8]);
        gload16(Wb + ko,            &Bs[tid*8]);
        gload16(Wb + 64*C_ + ko,    &Bs[2048 + tid*8]);
        __syncthreads();
        short8 af[4], bfr[4];
        #pragma unroll
        for (int i = 0; i < 4; ++i) {
            af[i]  = *reinterpret_cast<const short8*>(&As[(wr*64 + i*16 + fr)*32 + fq*8]);
            bfr[i] = *reinterpret_cast<const short8*>(&Bs[(wc*64 + i*16 + fr)*32 + fq*8]);
        }
        #pragma unroll
        for (int i = 0; i < 4; ++i)
            #pragma unroll
            for (int j = 0; j < 4; ++j)
                acc[i][j] = __builtin_amdgcn_mfma_f32_16x16x32_bf16(af[i], bfr[j], acc[i][j], 0, 0, 0);
        __syncthreads();
    }

    float sc = (which == 1) ? 0.03125f : 1.0f;   // fold 1/sqrt(C)=1/32 into Q
    int mbase = bm*128 + wr*64;
    int nbase = bn*128 + wc*64;
    #pragma unroll
    for (int j = 0; j < 4; ++j) {
        int col = nbase + j*16 + fr;
        float bv = bias[col];
        int h = col >> 6, d = col & 63;
        #pragma unroll
        for (int i = 0; i < 4; ++i) {
            int r0 = mbase + i*16 + fq*4;
            #pragma unroll
            for (int r = 0; r < 4; ++r) {
                float v = (acc[i][j][r] + bv) * sc;
                int m = r0 + r;
                int b = m >> 11, t = m & (T_-1);
                unsigned short hv = f2bf(v);
                if (which == 2)
                    o2[((size_t)(b*H_ + h)*D_ + d)*T_ + t] = hv;
                else {
                    unsigned short* o = (which==0) ? o0 : o1;
                    o[((size_t)(b*H_ + h)*T_ + t)*D_ + d] = hv;
                }
            }
        }
    }
}

// ---------------- output projection GEMM ----------------
__global__ __launch_bounds__(256) void gemm_out(
    const unsigned short* __restrict__ A,   // y bf16 [M_][C_]
    const unsigned short* __restrict__ W,   // Wo bf16 [C_][C_]
    const float* __restrict__ bias,
    float* __restrict__ out)
{
    __shared__ unsigned short As[128*32];
    __shared__ unsigned short Bs[128*32];
    int bx = blockIdx.x;
    int bm = bx >> 3, bn = bx & 7;

    int tid = threadIdx.x;
    int lane = tid & 63;
    int fr = lane & 15, fq = lane >> 4;
    int wid = tid >> 6;
    int wr = wid >> 1, wc = wid & 1;

    int srow = tid >> 2;
    int scol = (tid & 3) << 3;
    const unsigned short* Ab = A + (size_t)(bm*128 + srow) * C_ + scol;
    const unsigned short* Wb = W + (size_t)(bn*128 + srow) * C_ + scol;

    f32x4 acc[4][4] = {};

    for (int kt = 0; kt < C_/32; ++kt) {
        int ko = kt*32;
        gload16(Ab + ko,            &As[tid*8]);
        gload16(Ab + 64*C_ + ko,    &As[2048 + tid*8]);
        gload16(Wb + ko,            &Bs[tid*8]);
        gload16(Wb + 64*C_ + ko,    &Bs[2048 + tid*8]);
        __syncthreads();
        short8 af[4], bfr[4];
        #pragma unroll
        for (int i = 0; i < 4; ++i) {
            af[i]  = *reinterpret_cast<const short8*>(&As[(wr*64 + i*16 + fr)*32 + fq*8]);
            bfr[i] = *reinterpret_cast<const short8*>(&Bs[(wc*64 + i*16 + fr)*32 + fq*8]);
        }
        #pragma unroll
        for (int i = 0; i < 4; ++i)
            #pragma unroll
            for (int j = 0; j < 4; ++j)
                acc[i][j] = __builtin_amdgcn_mfma_f32_16x16x32_bf16(af[i], bfr[j], acc[i][j], 0, 0, 0);
        __syncthreads();
    }

    int mbase = bm*128 + wr*64;
    int nbase = bn*128 + wc*64;
    #pragma unroll
    for (int j = 0; j < 4; ++j) {
        int col = nbase + j*16 + fr;
        float bv = bias[col];
        #pragma unroll
        for (int i = 0; i < 4; ++i) {
            int r0 = mbase + i*16 + fq*4;
            #pragma unroll
            for (int r = 0; r < 4; ++r)
                out[(size_t)(r0 + r)*C_ + col] = acc[i][j][r] + bv;
        }
    }
}

// ---------------- flash attention (causal), swapped-QK^T 32x32 ----------------
// q (pre-scaled), k: [B*H][T][D] bf16 ; vt: [B*H][D][T] bf16 ; y: [B*T][C] bf16
// One wave = 32 q rows. No LDS. Lane holds P-row for q = qblk*32 + (lane&31).
__global__ __launch_bounds__(256) void flash_attn(
    const unsigned short* __restrict__ q,
    const unsigned short* __restrict__ k,
    const unsigned short* __restrict__ vt,
    unsigned short* __restrict__ y)
{
    int tid = threadIdx.x, lane = tid & 63, wid = tid >> 6;
    int l31 = lane & 31, hi = lane >> 5;
    int bid = blockIdx.x;
    int bh   = (bid & 7) * 4 + wid;    // cluster 4 heads per XCD
    int qblk = 63 - (bid >> 3);        // heavy tiles first

    const unsigned short* qp = q  + ((size_t)bh*T_ + qblk*32) * D_;
    const unsigned short* kp = k  + (size_t)bh*T_*D_;
    const unsigned short* vp = vt + (size_t)bh*D_*T_;

    // Q B-fragments: col = l31 (q row), k = hi*8+i within 16-wide dk slice
    short8 qf[4];
    #pragma unroll
    for (int dk = 0; dk < 4; ++dk)
        qf[dk] = *reinterpret_cast<const short8*>(qp + (size_t)l31*D_ + dk*16 + hi*8);

    f32x16 o0 = {}, o1 = {};
    float m_ = -1e30f, l_ = 0.f;
    int qrow = qblk*32 + l31;
    const float LOG2E = 1.44269504f;

    int nsteps = (qblk >> 1) + 1;

    for (int s = 0; s < nsteps; ++s) {
        int kv0 = s*64;
        // ---- QK^T (swapped: A=K, B=Q) -> a[t]: col=q row, row=kv ----
        f32x16 a[2] = {};
        #pragma unroll
        for (int dk = 0; dk < 4; ++dk) {
            short8 kf0 = *reinterpret_cast<const short8*>(kp + (size_t)(kv0 + l31)*D_      + dk*16 + hi*8);
            short8 kf1 = *reinterpret_cast<const short8*>(kp + (size_t)(kv0 + 32 + l31)*D_ + dk*16 + hi*8);
            a[0] = __builtin_amdgcn_mfma_f32_32x32x16_bf16(kf0, qf[dk], a[0], 0, 0, 0);
            a[1] = __builtin_amdgcn_mfma_f32_32x32x16_bf16(kf1, qf[dk], a[1], 0, 0, 0);
        }
        // ---- V fragment loads (issued early; consumed after softmax) ----
        short8 vf0[4], vf1[4];
        #pragma unroll
        for (int kb = 0; kb < 4; ++kb) {
            vf0[kb] = *reinterpret_cast<const short8*>(vp + (size_t)l31*T_        + kv0 + kb*16 + hi*8);
            vf1[kb] = *reinterpret_cast<const short8*>(vp + (size_t)(32 + l31)*T_ + kv0 + kb*16 + hi*8);
        }
        // ---- to log2 domain + causal mask ----
        #pragma unroll
        for (int t = 0; t < 2; ++t)
            #pragma unroll
            for (int r = 0; r < 16; ++r) {
                int kv = kv0 + t*32 + (r&3) + 8*(r>>2) + 4*hi;
                float v = a[t][r] * LOG2E;
                a[t][r] = (kv > qrow) ? -1e30f : v;
            }
        // ---- row max: in-lane tree + cross-half ----
        float pm = a[0][0];
        #pragma unroll
        for (int r = 1; r < 16; ++r) pm = fmaxf(pm, a[0][r]);
        #pragma unroll
        for (int r = 0; r < 16; ++r) pm = fmaxf(pm, a[1][r]);
        pm = fmaxf(pm, __shfl_xor(pm, 32));

        // ---- defer-max (T13): rescale only when max grows past THR ----
        if (!__all(pm - m_ <= 8.0f)) {
            float mn = fmaxf(m_, pm);
            float alpha = exp2f(m_ - mn);
            l_ *= alpha;
            m_ = mn;
            #pragma unroll
            for (int r = 0; r < 16; ++r) {
                int row = (r&3) + 8*(r>>2) + 4*hi;
                float ar = __shfl(alpha, row);
                o0[r] *= ar;
                o1[r] *= ar;
            }
        }
        // ---- P = exp2(s - m), row sum ----
        float rs = 0.f;
        #pragma unroll
        for (int t = 0; t < 2; ++t)
            #pragma unroll
            for (int r = 0; r < 16; ++r) {
                float p = exp2f(a[t][r] - m_);
                a[t][r] = p;
                rs += p;
            }
        rs += __shfl_xor(rs, 32);
        l_ += rs;

        // ---- pack P to bf16 pairs ----
        unsigned pk_[2][8];
        #pragma unroll
        for (int t = 0; t < 2; ++t)
            #pragma unroll
            for (int jj = 0; jj < 8; ++jj)
                pk_[t][jj] = cvtpk_bf16(a[t][2*jj], a[t][2*jj+1]);

        // ---- PV: build A-frags via half-exchange, MFMA ----
        #pragma unroll
        for (int kb = 0; kb < 4; ++kb) {
            const int t = kb >> 1;
            const int ab = 4*(kb & 1);
            unsigned p0 = pk_[t][ab], p1 = pk_[t][ab+1], p2 = pk_[t][ab+2], p3 = pk_[t][ab+3];
            unsigned send0 = hi ? p0 : p2, send1 = hi ? p1 : p3;
            unsigned own0  = hi ? p2 : p0, own1  = hi ? p3 : p1;
            unsigned cr0 = (unsigned)__shfl_xor((int)send0, 32);
            unsigned cr1 = (unsigned)__shfl_xor((int)send1, 32);
            u32x4 wv;
            wv.x = hi ? cr0 : own0;   // elements 0-3 (src half 0)
            wv.y = hi ? cr1 : own1;
            wv.z = hi ? own0 : cr0;   // elements 4-7 (src half 1)
            wv.w = hi ? own1 : cr1;
            short8 pfrag = __builtin_bit_cast(short8, wv);
            o0 = __builtin_amdgcn_mfma_f32_32x32x16_bf16(pfrag, vf0[kb], o0, 0, 0, 0);
            o1 = __builtin_amdgcn_mfma_f32_32x32x16_bf16(pfrag, vf1[kb], o1, 0, 0, 0);
        }
    }

    // ---- epilogue: normalize, write y ----
    float inv = 1.0f / l_;            // for q row = l31 (both halves hold it)
    int b = bh >> 4, h = bh & 15;
    #pragma unroll
    for (int r = 0; r < 16; ++r) {
        int row = (r&3) + 8*(r>>2) + 4*hi;
        float ir = __shfl(inv, row);
        int trow = qblk*32 + row;
        size_t base = ((size_t)(b*T_ + trow))*C_ + h*64;
        y[base + l31]      = f2bf(o0[r] * ir);
        y[base + 32 + l31] = f2bf(o1[r] * ir);
    }
}

extern "C" void kernel_launch(void* const* d_in, const int* in_sizes, int n_in,
                              void* d_out, int out_size, void* d_ws, size_t ws_size,
                              hipStream_t stream) {
    const float* x  = (const float*)d_in[0];
    const float* Wk = (const float*)d_in[1];
    const float* bk = (const float*)d_in[2];
    const float* Wq = (const float*)d_in[3];
    const float* bq = (const float*)d_in[4];
    const float* Wv = (const float*)d_in[5];
    const float* bv = (const float*)d_in[6];
    const float* Wo = (const float*)d_in[7];
    const float* bo = (const float*)d_in[8];
    float* out = (float*)d_out;

    char* ws = (char*)d_ws;
    unsigned short* xb  = (unsigned short*)(ws);                    // 8MB
    unsigned short* wkb = (unsigned short*)(ws + ((size_t)8  << 20));
    unsigned short* wqb = (unsigned short*)(ws + ((size_t)10 << 20));
    unsigned short* wvb = (unsigned short*)(ws + ((size_t)12 << 20));
    unsigned short* wob = (unsigned short*)(ws + ((size_t)14 << 20));
    unsigned short* qb  = (unsigned short*)(ws + ((size_t)16 << 20)); // [B,H,T,D]
    unsigned short* kb  = (unsigned short*)(ws + ((size_t)24 << 20)); // [B,H,T,D]
    unsigned short* vtb = (unsigned short*)(ws + ((size_t)32 << 20)); // [B,H,D,T]
    unsigned short* yb  = (unsigned short*)(ws + ((size_t)40 << 20)); // [B*T,C]

    const int nx = B_*T_*C_;   // 4M
    const int nw = C_*C_;      // 1M

    cvt_bf16<<<dim3(nx/4/256), dim3(256), 0, stream>>>(x, xb, nx);
    cvt_bf16_w4<<<dim3(nw/4/256, 4), dim3(256), 0, stream>>>(
        Wk, Wq, Wv, Wo, wkb, wqb, wvb, wob, nw);

    gemm_qkv<<<dim3(768), dim3(256), 0, stream>>>(xb, wkb, wqb, wvb, bk, bq, bv, kb, qb, vtb);

    flash_attn<<<dim3(512), dim3(256), 0, stream>>>(qb, kb, vtb, yb);

    gemm_out<<<dim3(256), dim3(256), 0, stream>>>(yb, wob, bo, out);
}

// Round 3
// 156.296 us; speedup vs baseline: 1.9573x; 1.0841x over previous
//
#include <hip/hip_runtime.h>
#include <hip/hip_bf16.h>
#include <stdint.h>
#include <stddef.h>

#define B_ 2
#define T_ 2048
#define C_ 1024
#define H_ 16
#define D_ 64
#define M_ (B_*T_)   // 4096

typedef __attribute__((ext_vector_type(8))) short short8;
typedef __attribute__((ext_vector_type(4))) float f32x4;
typedef __attribute__((ext_vector_type(16))) float f32x16;
typedef __attribute__((ext_vector_type(4))) unsigned int u32x4;

__device__ __forceinline__ unsigned short f2bf(float f) {
    unsigned u = __float_as_uint(f);
    unsigned r = 0x7FFFu + ((u >> 16) & 1u);
    return (unsigned short)((u + r) >> 16);
}

__device__ __forceinline__ unsigned cvtpk_bf16(float lo, float hi) {
    unsigned r;
    asm("v_cvt_pk_bf16_f32 %0, %1, %2" : "=v"(r) : "v"(lo), "v"(hi));
    return r;
}

__device__ __forceinline__ void gload16(const void* g, void* l) {
    __builtin_amdgcn_global_load_lds(
        (__attribute__((address_space(1))) void*)g,
        (__attribute__((address_space(3))) void*)l,
        16, 0, 0);
}

// ---------------- fp32 -> bf16 conversion ----------------
__global__ void cvt_bf16(const float* __restrict__ in,
                         unsigned short* __restrict__ out, int n) {
    int idx = (blockIdx.x * blockDim.x + threadIdx.x) * 4;
    if (idx >= n) return;
    float4 v = *reinterpret_cast<const float4*>(in + idx);
    ushort4 o;
    o.x = f2bf(v.x); o.y = f2bf(v.y); o.z = f2bf(v.z); o.w = f2bf(v.w);
    *reinterpret_cast<ushort4*>(out + idx) = o;
}

__global__ void cvt_bf16_w4(const float* __restrict__ a, const float* __restrict__ b,
                            const float* __restrict__ c, const float* __restrict__ d,
                            unsigned short* __restrict__ oa, unsigned short* __restrict__ ob,
                            unsigned short* __restrict__ oc, unsigned short* __restrict__ od,
                            int n) {
    int idx = (blockIdx.x * blockDim.x + threadIdx.x) * 4;
    if (idx >= n) return;
    const float* in = (blockIdx.y == 0) ? a : (blockIdx.y == 1) ? b : (blockIdx.y == 2) ? c : d;
    unsigned short* out = (blockIdx.y == 0) ? oa : (blockIdx.y == 1) ? ob : (blockIdx.y == 2) ? oc : od;
    float4 v = *reinterpret_cast<const float4*>(in + idx);
    ushort4 o;
    o.x = f2bf(v.x); o.y = f2bf(v.y); o.z = f2bf(v.z); o.w = f2bf(v.w);
    *reinterpret_cast<ushort4*>(out + idx) = o;
}

// ---------------- fused QKV projection GEMM ----------------
// which 0 -> K [B,H,T,D], which 1 -> Q*scale [B,H,T,D], which 2 -> V^T [B,H,D,T]
__global__ __launch_bounds__(256) void gemm_qkv(
    const unsigned short* __restrict__ A,
    const unsigned short* __restrict__ W0,
    const unsigned short* __restrict__ W1,
    const unsigned short* __restrict__ W2,
    const float* __restrict__ b0,
    const float* __restrict__ b1,
    const float* __restrict__ b2,
    unsigned short* __restrict__ o0,   // k
    unsigned short* __restrict__ o1,   // q (pre-scaled by LOG2E/32)
    unsigned short* __restrict__ o2)   // vt
{
    __shared__ unsigned short As[128*32];
    __shared__ unsigned short Bs[128*32];
    int which = blockIdx.x >> 8;
    int bx = blockIdx.x & 255;
    int bm = bx >> 3, bn = bx & 7;
    const unsigned short* W = (which==0) ? W0 : ((which==1) ? W1 : W2);
    const float* bias = (which==0) ? b0 : ((which==1) ? b1 : b2);

    int tid = threadIdx.x;
    int lane = tid & 63;
    int fr = lane & 15, fq = lane >> 4;
    int wid = tid >> 6;
    int wr = wid >> 1, wc = wid & 1;

    int srow = tid >> 2;            // 0..63
    int scol = (tid & 3) << 3;      // 0,8,16,24
    const unsigned short* Ab = A + (size_t)(bm*128 + srow) * C_ + scol;
    const unsigned short* Wb = W + (size_t)(bn*128 + srow) * C_ + scol;

    f32x4 acc[4][4] = {};

    for (int kt = 0; kt < C_/32; ++kt) {
        int ko = kt*32;
        gload16(Ab + ko,            &As[tid*8]);
        gload16(Ab + 64*C_ + ko,    &As[2048 + tid*8]);
        gload16(Wb + ko,            &Bs[tid*8]);
        gload16(Wb + 64*C_ + ko,    &Bs[2048 + tid*8]);
        __syncthreads();
        short8 af[4], bfr[4];
        #pragma unroll
        for (int i = 0; i < 4; ++i) {
            af[i]  = *reinterpret_cast<const short8*>(&As[(wr*64 + i*16 + fr)*32 + fq*8]);
            bfr[i] = *reinterpret_cast<const short8*>(&Bs[(wc*64 + i*16 + fr)*32 + fq*8]);
        }
        #pragma unroll
        for (int i = 0; i < 4; ++i)
            #pragma unroll
            for (int j = 0; j < 4; ++j)
                acc[i][j] = __builtin_amdgcn_mfma_f32_16x16x32_bf16(af[i], bfr[j], acc[i][j], 0, 0, 0);
        __syncthreads();
    }

    // Q: fold 1/sqrt(C)=1/32 AND log2(e) so QK^T lands in log2 domain
    float sc = (which == 1) ? 0.045084220f : 1.0f;
    int mbase = bm*128 + wr*64;
    int nbase = bn*128 + wc*64;
    #pragma unroll
    for (int j = 0; j < 4; ++j) {
        int col = nbase + j*16 + fr;
        float bv = bias[col];
        int h = col >> 6, d = col & 63;
        #pragma unroll
        for (int i = 0; i < 4; ++i) {
            int r0 = mbase + i*16 + fq*4;
            #pragma unroll
            for (int r = 0; r < 4; ++r) {
                float v = (acc[i][j][r] + bv) * sc;
                int m = r0 + r;
                int b = m >> 11, t = m & (T_-1);
                unsigned short hv = f2bf(v);
                if (which == 2)
                    o2[((size_t)(b*H_ + h)*D_ + d)*T_ + t] = hv;
                else {
                    unsigned short* o = (which==0) ? o0 : o1;
                    o[((size_t)(b*H_ + h)*T_ + t)*D_ + d] = hv;
                }
            }
        }
    }
}

// ---------------- output projection GEMM ----------------
__global__ __launch_bounds__(256) void gemm_out(
    const unsigned short* __restrict__ A,   // y bf16 [M_][C_]
    const unsigned short* __restrict__ W,   // Wo bf16 [C_][C_]
    const float* __restrict__ bias,
    float* __restrict__ out)
{
    __shared__ unsigned short As[128*32];
    __shared__ unsigned short Bs[128*32];
    int bx = blockIdx.x;
    int bm = bx >> 3, bn = bx & 7;

    int tid = threadIdx.x;
    int lane = tid & 63;
    int fr = lane & 15, fq = lane >> 4;
    int wid = tid >> 6;
    int wr = wid >> 1, wc = wid & 1;

    int srow = tid >> 2;
    int scol = (tid & 3) << 3;
    const unsigned short* Ab = A + (size_t)(bm*128 + srow) * C_ + scol;
    const unsigned short* Wb = W + (size_t)(bn*128 + srow) * C_ + scol;

    f32x4 acc[4][4] = {};

    for (int kt = 0; kt < C_/32; ++kt) {
        int ko = kt*32;
        gload16(Ab + ko,            &As[tid*8]);
        gload16(Ab + 64*C_ + ko,    &As[2048 + tid*8]);
        gload16(Wb + ko,            &Bs[tid*8]);
        gload16(Wb + 64*C_ + ko,    &Bs[2048 + tid*8]);
        __syncthreads();
        short8 af[4], bfr[4];
        #pragma unroll
        for (int i = 0; i < 4; ++i) {
            af[i]  = *reinterpret_cast<const short8*>(&As[(wr*64 + i*16 + fr)*32 + fq*8]);
            bfr[i] = *reinterpret_cast<const short8*>(&Bs[(wc*64 + i*16 + fr)*32 + fq*8]);
        }
        #pragma unroll
        for (int i = 0; i < 4; ++i)
            #pragma unroll
            for (int j = 0; j < 4; ++j)
                acc[i][j] = __builtin_amdgcn_mfma_f32_16x16x32_bf16(af[i], bfr[j], acc[i][j], 0, 0, 0);
        __syncthreads();
    }

    int mbase = bm*128 + wr*64;
    int nbase = bn*128 + wc*64;
    #pragma unroll
    for (int j = 0; j < 4; ++j) {
        int col = nbase + j*16 + fr;
        float bv = bias[col];
        #pragma unroll
        for (int i = 0; i < 4; ++i) {
            int r0 = mbase + i*16 + fq*4;
            #pragma unroll
            for (int r = 0; r < 4; ++r)
                out[(size_t)(r0 + r)*C_ + col] = acc[i][j][r] + bv;
        }
    }
}

// ---------------- flash attention (causal), swapped-QK^T 32x32, 2-way KV split ----------------
// q (pre-scaled by LOG2E/32), k: [B*H][T][D] bf16 ; vt: [B*H][D][T] bf16 ; y: [B*T][C] bf16
// Block = 4 waves = 2 units (bh pair); each unit = 2 waves splitting the KV range.
__device__ __forceinline__ void attn_tile(
    int kv0, bool isLast, int l31, int hi,
    const unsigned short* __restrict__ kp,
    const unsigned short* __restrict__ vp,
    const short8 (&qf)[4], const short8 (&kcur)[4], short8 (&knxt)[4],
    f32x16& o0, f32x16& o1, float& m_, float& l_)
{
    // prefetch next tile's K fragments (flies during softmax+PV)
    const unsigned short* kr = kp + (size_t)(kv0 + 32 + l31) * D_ + hi*8;
    knxt[0] = *reinterpret_cast<const short8*>(kr);
    knxt[1] = *reinterpret_cast<const short8*>(kr + 16);
    knxt[2] = *reinterpret_cast<const short8*>(kr + 32);
    knxt[3] = *reinterpret_cast<const short8*>(kr + 48);

    // QK^T (swapped: A=K, B=Q): a0 col = q row (l31), row = kv_local
    f32x16 a0 = {};
    a0 = __builtin_amdgcn_mfma_f32_32x32x16_bf16(kcur[0], qf[0], a0, 0, 0, 0);
    a0 = __builtin_amdgcn_mfma_f32_32x32x16_bf16(kcur[1], qf[1], a0, 0, 0, 0);
    a0 = __builtin_amdgcn_mfma_f32_32x32x16_bf16(kcur[2], qf[2], a0, 0, 0, 0);
    a0 = __builtin_amdgcn_mfma_f32_32x32x16_bf16(kcur[3], qf[3], a0, 0, 0, 0);

    // V fragment loads (issued early; consumed after softmax)
    short8 vf0[2], vf1[2];
    const unsigned short* vr0 = vp + (size_t)l31*T_ + kv0 + hi*8;
    const unsigned short* vr1 = vp + (size_t)(32 + l31)*T_ + kv0 + hi*8;
    vf0[0] = *reinterpret_cast<const short8*>(vr0);
    vf0[1] = *reinterpret_cast<const short8*>(vr0 + 16);
    vf1[0] = *reinterpret_cast<const short8*>(vr1);
    vf1[1] = *reinterpret_cast<const short8*>(vr1 + 16);

    // causal mask: only the diagonal tile needs it; pattern is lane-static
    if (isLast) {
        #pragma unroll
        for (int r = 0; r < 16; ++r) {
            int kvl = (r&3) + 8*(r>>2) + 4*hi;
            if (kvl > l31) a0[r] = -1e30f;
        }
    }

    // row max (scores already in log2 domain)
    float pm = a0[0];
    #pragma unroll
    for (int r = 1; r < 16; ++r) pm = fmaxf(pm, a0[r]);
    pm = fmaxf(pm, __shfl_xor(pm, 32));

    // defer-max (T13)
    if (!__all(pm - m_ <= 8.0f)) {
        float mn = fmaxf(m_, pm);
        float alpha = exp2f(m_ - mn);
        l_ *= alpha;
        m_ = mn;
        #pragma unroll
        for (int r = 0; r < 16; ++r) {
            int row = (r&3) + 8*(r>>2) + 4*hi;
            float ar = __shfl(alpha, row);
            o0[r] *= ar;
            o1[r] *= ar;
        }
    }

    // P = exp2(s - m), row sum
    float rs = 0.f;
    #pragma unroll
    for (int r = 0; r < 16; ++r) {
        float p = exp2f(a0[r] - m_);
        a0[r] = p;
        rs += p;
    }
    rs += __shfl_xor(rs, 32);
    l_ += rs;

    // pack P to bf16 pairs
    unsigned pk_[8];
    #pragma unroll
    for (int jj = 0; jj < 8; ++jj)
        pk_[jj] = cvtpk_bf16(a0[2*jj], a0[2*jj+1]);

    // PV: build A-frags via half-exchange, MFMA
    #pragma unroll
    for (int kb = 0; kb < 2; ++kb) {
        unsigned p0 = pk_[4*kb], p1 = pk_[4*kb+1], p2 = pk_[4*kb+2], p3 = pk_[4*kb+3];
        unsigned send0 = hi ? p0 : p2, send1 = hi ? p1 : p3;
        unsigned own0  = hi ? p2 : p0, own1  = hi ? p3 : p1;
        unsigned cr0 = (unsigned)__shfl_xor((int)send0, 32);
        unsigned cr1 = (unsigned)__shfl_xor((int)send1, 32);
        u32x4 wv;
        wv.x = hi ? cr0 : own0;
        wv.y = hi ? cr1 : own1;
        wv.z = hi ? own0 : cr0;
        wv.w = hi ? own1 : cr1;
        short8 pfrag = __builtin_bit_cast(short8, wv);
        o0 = __builtin_amdgcn_mfma_f32_32x32x16_bf16(pfrag, vf0[kb], o0, 0, 0, 0);
        o1 = __builtin_amdgcn_mfma_f32_32x32x16_bf16(pfrag, vf1[kb], o1, 0, 0, 0);
    }
}

__global__ __launch_bounds__(256, 4) void flash_attn(
    const unsigned short* __restrict__ q,
    const unsigned short* __restrict__ k,
    const unsigned short* __restrict__ vt,
    unsigned short* __restrict__ y)
{
    __shared__ float oLDS[2][8][64][4];   // pair, chunk, lane, 4 f32 = 16 KB
    __shared__ float mlLDS[2][2][64];     // pair, {m,l}, lane = 1 KB

    int tid = threadIdx.x, lane = tid & 63, wid = tid >> 6;
    int l31 = lane & 31, hi = lane >> 5;
    int pair = wid >> 1, split = wid & 1;
    int bid = blockIdx.x;

    int qblk = 63 - (bid >> 4);                              // heavy first
    int bh   = (bid & 7)*4 + ((bid >> 3) & 1)*2 + pair;      // head-clustered per XCD

    const unsigned short* qp = q  + ((size_t)bh*T_ + qblk*32) * D_;
    const unsigned short* kp = k  + (size_t)bh*T_*D_;
    const unsigned short* vp = vt + (size_t)bh*D_*T_;

    short8 qf[4];
    #pragma unroll
    for (int dk = 0; dk < 4; ++dk)
        qf[dk] = *reinterpret_cast<const short8*>(qp + (size_t)l31*D_ + dk*16 + hi*8);

    f32x16 o0 = {}, o1 = {};
    float m_ = -1e30f, l_ = 0.f;

    int nt = qblk + 1;
    int half = (nt + 1) >> 1;
    int t0 = split ? half : 0;
    int t1 = split ? nt : half;

    if (t0 < t1) {
        short8 kfA[4], kfB[4];
        const unsigned short* kr = kp + (size_t)(t0*32 + l31) * D_ + hi*8;
        kfA[0] = *reinterpret_cast<const short8*>(kr);
        kfA[1] = *reinterpret_cast<const short8*>(kr + 16);
        kfA[2] = *reinterpret_cast<const short8*>(kr + 32);
        kfA[3] = *reinterpret_cast<const short8*>(kr + 48);

        int ti = t0;
        while (ti + 2 <= t1) {
            attn_tile(ti*32, ti == nt-1, l31, hi, kp, vp, qf, kfA, kfB, o0, o1, m_, l_); ++ti;
            attn_tile(ti*32, ti == nt-1, l31, hi, kp, vp, qf, kfB, kfA, o0, o1, m_, l_); ++ti;
        }
        if (ti < t1) {
            attn_tile(ti*32, ti == nt-1, l31, hi, kp, vp, qf, kfA, kfB, o0, o1, m_, l_); ++ti;
        }
    }

    // ---- merge the two KV-splits via LDS ----
    if (!split) {
        #pragma unroll
        for (int c = 0; c < 4; ++c) {
            float4 v0 = make_float4(o0[4*c], o0[4*c+1], o0[4*c+2], o0[4*c+3]);
            float4 v1 = make_float4(o1[4*c], o1[4*c+1], o1[4*c+2], o1[4*c+3]);
            *reinterpret_cast<float4*>(&oLDS[pair][c][lane][0])   = v0;
            *reinterpret_cast<float4*>(&oLDS[pair][4+c][lane][0]) = v1;
        }
        mlLDS[pair][0][lane] = m_;
        mlLDS[pair][1][lane] = l_;
    }
    __syncthreads();
    if (split) {
        float mA = mlLDS[pair][0][lane];
        float lA = mlLDS[pair][1][lane];
        float mN = fmaxf(mA, m_);
        float aA = exp2f(mA - mN);
        float aB = exp2f(m_ - mN);
        float lN = lA*aA + l_*aB;
        float inv = 1.0f / lN;
        float cA = aA * inv, cB = aB * inv;

        float vals0[16], vals1[16];
        #pragma unroll
        for (int c = 0; c < 4; ++c) {
            *reinterpret_cast<float4*>(&vals0[4*c]) = *reinterpret_cast<float4*>(&oLDS[pair][c][lane][0]);
            *reinterpret_cast<float4*>(&vals1[4*c]) = *reinterpret_cast<float4*>(&oLDS[pair][4+c][lane][0]);
        }

        int b = bh >> 4, h = bh & 15;
        #pragma unroll
        for (int r = 0; r < 16; ++r) {
            int row = (r&3) + 8*(r>>2) + 4*hi;
            float cAr = __shfl(cA, row);
            float cBr = __shfl(cB, row);
            int trow = qblk*32 + row;
            size_t base = ((size_t)(b*T_ + trow))*C_ + h*64;
            y[base + l31]      = f2bf(vals0[r]*cAr + o0[r]*cBr);
            y[base + 32 + l31] = f2bf(vals1[r]*cAr + o1[r]*cBr);
        }
    }
}

extern "C" void kernel_launch(void* const* d_in, const int* in_sizes, int n_in,
                              void* d_out, int out_size, void* d_ws, size_t ws_size,
                              hipStream_t stream) {
    const float* x  = (const float*)d_in[0];
    const float* Wk = (const float*)d_in[1];
    const float* bk = (const float*)d_in[2];
    const float* Wq = (const float*)d_in[3];
    const float* bq = (const float*)d_in[4];
    const float* Wv = (const float*)d_in[5];
    const float* bv = (const float*)d_in[6];
    const float* Wo = (const float*)d_in[7];
    const float* bo = (const float*)d_in[8];
    float* out = (float*)d_out;

    char* ws = (char*)d_ws;
    unsigned short* xb  = (unsigned short*)(ws);                    // 8MB
    unsigned short* wkb = (unsigned short*)(ws + ((size_t)8  << 20));
    unsigned short* wqb = (unsigned short*)(ws + ((size_t)10 << 20));
    unsigned short* wvb = (unsigned short*)(ws + ((size_t)12 << 20));
    unsigned short* wob = (unsigned short*)(ws + ((size_t)14 << 20));
    unsigned short* qb  = (unsigned short*)(ws + ((size_t)16 << 20)); // [B,H,T,D]
    unsigned short* kb  = (unsigned short*)(ws + ((size_t)24 << 20)); // [B,H,T,D]
    unsigned short* vtb = (unsigned short*)(ws + ((size_t)32 << 20)); // [B,H,D,T]
    unsigned short* yb  = (unsigned short*)(ws + ((size_t)40 << 20)); // [B*T,C]

    const int nx = B_*T_*C_;   // 4M
    const int nw = C_*C_;      // 1M

    cvt_bf16<<<dim3(nx/4/256), dim3(256), 0, stream>>>(x, xb, nx);
    cvt_bf16_w4<<<dim3(nw/4/256, 4), dim3(256), 0, stream>>>(
        Wk, Wq, Wv, Wo, wkb, wqb, wvb, wob, nw);

    gemm_qkv<<<dim3(768), dim3(256), 0, stream>>>(xb, wkb, wqb, wvb, bk, bq, bv, kb, qb, vtb);

    flash_attn<<<dim3(1024), dim3(256), 0, stream>>>(qb, kb, vtb, yb);

    gemm_out<<<dim3(256), dim3(256), 0, stream>>>(yb, wob, bo, out);
}

// Round 4
// 148.280 us; speedup vs baseline: 2.0631x; 1.0541x over previous
//
#include <hip/hip_runtime.h>
#include <hip/hip_bf16.h>
#include <stdint.h>
#include <stddef.h>

#define B_ 2
#define T_ 2048
#define C_ 1024
#define H_ 16
#define D_ 64
#define M_ (B_*T_)   // 4096

typedef __attribute__((ext_vector_type(8))) short short8;
typedef __attribute__((ext_vector_type(4))) float f32x4;
typedef __attribute__((ext_vector_type(16))) float f32x16;
typedef __attribute__((ext_vector_type(4))) unsigned int u32x4;

__device__ __forceinline__ unsigned short f2bf(float f) {
    unsigned u = __float_as_uint(f);
    unsigned r = 0x7FFFu + ((u >> 16) & 1u);
    return (unsigned short)((u + r) >> 16);
}

__device__ __forceinline__ unsigned cvtpk_bf16(float lo, float hi) {
    unsigned r;
    asm("v_cvt_pk_bf16_f32 %0, %1, %2" : "=v"(r) : "v"(lo), "v"(hi));
    return r;
}

// v_permlane32_swap_b32: dst.lanes[32:63] <-> src.lanes[0:31]
// after: a = [a_lo | b_lo], b = [a_hi | b_hi]
__device__ __forceinline__ void plswap(unsigned &a, unsigned &b) {
    asm("v_permlane32_swap_b32 %0, %1" : "+v"(a), "+v"(b));
}

// every lane ends with {own, partner(lane^32)} in some order -> reduce
__device__ __forceinline__ float xhalf_max(float v) {
    float a = v, b = v;
    asm("" : "+v"(b));   // force distinct register
    asm("v_permlane32_swap_b32 %0, %1" : "+v"(a), "+v"(b));
    return fmaxf(a, b);
}
__device__ __forceinline__ float xhalf_sum(float v) {
    float a = v, b = v;
    asm("" : "+v"(b));
    asm("v_permlane32_swap_b32 %0, %1" : "+v"(a), "+v"(b));
    return a + b;
}

__device__ __forceinline__ void gload16(const void* g, void* l) {
    __builtin_amdgcn_global_load_lds(
        (__attribute__((address_space(1))) void*)g,
        (__attribute__((address_space(3))) void*)l,
        16, 0, 0);
}

// ---------------- fp32 -> bf16 conversion ----------------
__global__ void cvt_bf16(const float* __restrict__ in,
                         unsigned short* __restrict__ out, int n) {
    int idx = (blockIdx.x * blockDim.x + threadIdx.x) * 4;
    if (idx >= n) return;
    float4 v = *reinterpret_cast<const float4*>(in + idx);
    ushort4 o;
    o.x = f2bf(v.x); o.y = f2bf(v.y); o.z = f2bf(v.z); o.w = f2bf(v.w);
    *reinterpret_cast<ushort4*>(out + idx) = o;
}

__global__ void cvt_bf16_w4(const float* __restrict__ a, const float* __restrict__ b,
                            const float* __restrict__ c, const float* __restrict__ d,
                            unsigned short* __restrict__ oa, unsigned short* __restrict__ ob,
                            unsigned short* __restrict__ oc, unsigned short* __restrict__ od,
                            int n) {
    int idx = (blockIdx.x * blockDim.x + threadIdx.x) * 4;
    if (idx >= n) return;
    const float* in = (blockIdx.y == 0) ? a : (blockIdx.y == 1) ? b : (blockIdx.y == 2) ? c : d;
    unsigned short* out = (blockIdx.y == 0) ? oa : (blockIdx.y == 1) ? ob : (blockIdx.y == 2) ? oc : od;
    float4 v = *reinterpret_cast<const float4*>(in + idx);
    ushort4 o;
    o.x = f2bf(v.x); o.y = f2bf(v.y); o.z = f2bf(v.z); o.w = f2bf(v.w);
    *reinterpret_cast<ushort4*>(out + idx) = o;
}

// ---------------- fused QKV projection GEMM ----------------
// which 0 -> K [B,H,T,D], which 1 -> Q*scale [B,H,T,D], which 2 -> V^T [B,H,D,T]
__global__ __launch_bounds__(256) void gemm_qkv(
    const unsigned short* __restrict__ A,
    const unsigned short* __restrict__ W0,
    const unsigned short* __restrict__ W1,
    const unsigned short* __restrict__ W2,
    const float* __restrict__ b0,
    const float* __restrict__ b1,
    const float* __restrict__ b2,
    unsigned short* __restrict__ o0,   // k
    unsigned short* __restrict__ o1,   // q (pre-scaled by LOG2E/32)
    unsigned short* __restrict__ o2)   // vt
{
    __shared__ unsigned short As[128*32];
    __shared__ unsigned short Bs[128*32];
    int which = blockIdx.x >> 8;
    int bx = blockIdx.x & 255;
    int bm = bx >> 3, bn = bx & 7;
    const unsigned short* W = (which==0) ? W0 : ((which==1) ? W1 : W2);
    const float* bias = (which==0) ? b0 : ((which==1) ? b1 : b2);

    int tid = threadIdx.x;
    int lane = tid & 63;
    int fr = lane & 15, fq = lane >> 4;
    int wid = tid >> 6;
    int wr = wid >> 1, wc = wid & 1;

    int srow = tid >> 2;            // 0..63
    int scol = (tid & 3) << 3;      // 0,8,16,24
    const unsigned short* Ab = A + (size_t)(bm*128 + srow) * C_ + scol;
    const unsigned short* Wb = W + (size_t)(bn*128 + srow) * C_ + scol;

    f32x4 acc[4][4] = {};

    for (int kt = 0; kt < C_/32; ++kt) {
        int ko = kt*32;
        gload16(Ab + ko,            &As[tid*8]);
        gload16(Ab + 64*C_ + ko,    &As[2048 + tid*8]);
        gload16(Wb + ko,            &Bs[tid*8]);
        gload16(Wb + 64*C_ + ko,    &Bs[2048 + tid*8]);
        __syncthreads();
        short8 af[4], bfr[4];
        #pragma unroll
        for (int i = 0; i < 4; ++i) {
            af[i]  = *reinterpret_cast<const short8*>(&As[(wr*64 + i*16 + fr)*32 + fq*8]);
            bfr[i] = *reinterpret_cast<const short8*>(&Bs[(wc*64 + i*16 + fr)*32 + fq*8]);
        }
        #pragma unroll
        for (int i = 0; i < 4; ++i)
            #pragma unroll
            for (int j = 0; j < 4; ++j)
                acc[i][j] = __builtin_amdgcn_mfma_f32_16x16x32_bf16(af[i], bfr[j], acc[i][j], 0, 0, 0);
        __syncthreads();
    }

    // Q: fold 1/sqrt(C)=1/32 AND log2(e) so QK^T lands in log2 domain
    float sc = (which == 1) ? 0.045084220f : 1.0f;
    int mbase = bm*128 + wr*64;
    int nbase = bn*128 + wc*64;
    #pragma unroll
    for (int j = 0; j < 4; ++j) {
        int col = nbase + j*16 + fr;
        float bv = bias[col];
        int h = col >> 6, d = col & 63;
        #pragma unroll
        for (int i = 0; i < 4; ++i) {
            int r0 = mbase + i*16 + fq*4;
            #pragma unroll
            for (int r = 0; r < 4; ++r) {
                float v = (acc[i][j][r] + bv) * sc;
                int m = r0 + r;
                int b = m >> 11, t = m & (T_-1);
                unsigned short hv = f2bf(v);
                if (which == 2)
                    o2[((size_t)(b*H_ + h)*D_ + d)*T_ + t] = hv;
                else {
                    unsigned short* o = (which==0) ? o0 : o1;
                    o[((size_t)(b*H_ + h)*T_ + t)*D_ + d] = hv;
                }
            }
        }
    }
}

// ---------------- output projection GEMM ----------------
__global__ __launch_bounds__(256) void gemm_out(
    const unsigned short* __restrict__ A,   // y bf16 [M_][C_]
    const unsigned short* __restrict__ W,   // Wo bf16 [C_][C_]
    const float* __restrict__ bias,
    float* __restrict__ out)
{
    __shared__ unsigned short As[128*32];
    __shared__ unsigned short Bs[128*32];
    int bx = blockIdx.x;
    int bm = bx >> 3, bn = bx & 7;

    int tid = threadIdx.x;
    int lane = tid & 63;
    int fr = lane & 15, fq = lane >> 4;
    int wid = tid >> 6;
    int wr = wid >> 1, wc = wid & 1;

    int srow = tid >> 2;
    int scol = (tid & 3) << 3;
    const unsigned short* Ab = A + (size_t)(bm*128 + srow) * C_ + scol;
    const unsigned short* Wb = W + (size_t)(bn*128 + srow) * C_ + scol;

    f32x4 acc[4][4] = {};

    for (int kt = 0; kt < C_/32; ++kt) {
        int ko = kt*32;
        gload16(Ab + ko,            &As[tid*8]);
        gload16(Ab + 64*C_ + ko,    &As[2048 + tid*8]);
        gload16(Wb + ko,            &Bs[tid*8]);
        gload16(Wb + 64*C_ + ko,    &Bs[2048 + tid*8]);
        __syncthreads();
        short8 af[4], bfr[4];
        #pragma unroll
        for (int i = 0; i < 4; ++i) {
            af[i]  = *reinterpret_cast<const short8*>(&As[(wr*64 + i*16 + fr)*32 + fq*8]);
            bfr[i] = *reinterpret_cast<const short8*>(&Bs[(wc*64 + i*16 + fr)*32 + fq*8]);
        }
        #pragma unroll
        for (int i = 0; i < 4; ++i)
            #pragma unroll
            for (int j = 0; j < 4; ++j)
                acc[i][j] = __builtin_amdgcn_mfma_f32_16x16x32_bf16(af[i], bfr[j], acc[i][j], 0, 0, 0);
        __syncthreads();
    }

    int mbase = bm*128 + wr*64;
    int nbase = bn*128 + wc*64;
    #pragma unroll
    for (int j = 0; j < 4; ++j) {
        int col = nbase + j*16 + fr;
        float bv = bias[col];
        #pragma unroll
        for (int i = 0; i < 4; ++i) {
            int r0 = mbase + i*16 + fq*4;
            #pragma unroll
            for (int r = 0; r < 4; ++r)
                out[(size_t)(r0 + r)*C_ + col] = acc[i][j][r] + bv;
        }
    }
}

// ---------------- flash attention (causal), swapped-QK^T 32x32, 2-way KV split ----------------
// q (pre-scaled by LOG2E/32), k: [B*H][T][D] bf16 ; vt: [B*H][D][T] bf16 ; y: [B*T][C] bf16
__device__ __forceinline__ void attn_tile(
    int kv0, bool isLast, int l31, int hi,
    const unsigned short* __restrict__ kp,
    const unsigned short* __restrict__ vp,
    const short8 (&qf)[4], const short8 (&kcur)[4], short8 (&knxt)[4],
    f32x16& o0, f32x16& o1, float& m_, float& l_)
{
    // prefetch next tile's K fragments (flies during softmax+PV)
    const unsigned short* kr = kp + (size_t)(kv0 + 32 + l31) * D_ + hi*8;
    knxt[0] = *reinterpret_cast<const short8*>(kr);
    knxt[1] = *reinterpret_cast<const short8*>(kr + 16);
    knxt[2] = *reinterpret_cast<const short8*>(kr + 32);
    knxt[3] = *reinterpret_cast<const short8*>(kr + 48);

    // QK^T (swapped: A=K, B=Q): a0 col = q row (l31), row = kv_local
    f32x16 a0 = {};
    __builtin_amdgcn_s_setprio(1);
    a0 = __builtin_amdgcn_mfma_f32_32x32x16_bf16(kcur[0], qf[0], a0, 0, 0, 0);
    a0 = __builtin_amdgcn_mfma_f32_32x32x16_bf16(kcur[1], qf[1], a0, 0, 0, 0);
    a0 = __builtin_amdgcn_mfma_f32_32x32x16_bf16(kcur[2], qf[2], a0, 0, 0, 0);
    a0 = __builtin_amdgcn_mfma_f32_32x32x16_bf16(kcur[3], qf[3], a0, 0, 0, 0);
    __builtin_amdgcn_s_setprio(0);

    // V fragment loads (issued early; consumed after softmax)
    short8 vf0[2], vf1[2];
    const unsigned short* vr0 = vp + (size_t)l31*T_ + kv0 + hi*8;
    const unsigned short* vr1 = vp + (size_t)(32 + l31)*T_ + kv0 + hi*8;
    vf0[0] = *reinterpret_cast<const short8*>(vr0);
    vf0[1] = *reinterpret_cast<const short8*>(vr0 + 16);
    vf1[0] = *reinterpret_cast<const short8*>(vr1);
    vf1[1] = *reinterpret_cast<const short8*>(vr1 + 16);

    // causal mask: only the diagonal tile needs it; pattern is lane-static
    if (isLast) {
        #pragma unroll
        for (int r = 0; r < 16; ++r) {
            int kvl = (r&3) + 8*(r>>2) + 4*hi;
            if (kvl > l31) a0[r] = -1e30f;
        }
    }

    // row max: pairwise tree (depth 4) + cross-half swap
    float x0 = fmaxf(a0[0], a0[1]),   x1 = fmaxf(a0[2], a0[3]);
    float x2 = fmaxf(a0[4], a0[5]),   x3 = fmaxf(a0[6], a0[7]);
    float x4 = fmaxf(a0[8], a0[9]),   x5 = fmaxf(a0[10], a0[11]);
    float x6 = fmaxf(a0[12], a0[13]), x7 = fmaxf(a0[14], a0[15]);
    float y0 = fmaxf(x0, x1), y1 = fmaxf(x2, x3), y2 = fmaxf(x4, x5), y3 = fmaxf(x6, x7);
    float pm = fmaxf(fmaxf(y0, y1), fmaxf(y2, y3));
    pm = xhalf_max(pm);

    // defer-max (T13)
    if (!__all(pm - m_ <= 8.0f)) {
        float mn = fmaxf(m_, pm);
        float alpha = exp2f(m_ - mn);
        l_ *= alpha;
        m_ = mn;
        #pragma unroll
        for (int r = 0; r < 16; ++r) {
            int row = (r&3) + 8*(r>>2) + 4*hi;
            float ar = __shfl(alpha, row);
            o0[r] *= ar;
            o1[r] *= ar;
        }
    }

    // P = exp2(s - m); row sum via pairwise tree + cross-half swap
    #pragma unroll
    for (int r = 0; r < 16; ++r)
        a0[r] = exp2f(a0[r] - m_);
    float s0 = a0[0]+a0[1],  s1 = a0[2]+a0[3],  s2 = a0[4]+a0[5],   s3 = a0[6]+a0[7];
    float s4 = a0[8]+a0[9],  s5 = a0[10]+a0[11], s6 = a0[12]+a0[13], s7 = a0[14]+a0[15];
    float u0 = s0+s1, u1 = s2+s3, u2 = s4+s5, u3 = s6+s7;
    float rs = (u0+u1) + (u2+u3);
    rs = xhalf_sum(rs);
    l_ += rs;

    // pack P to bf16 pairs
    unsigned pk_[8];
    #pragma unroll
    for (int jj = 0; jj < 8; ++jj)
        pk_[jj] = cvtpk_bf16(a0[2*jj], a0[2*jj+1]);

    // PV: A-frag redistribution via permlane32_swap (no DS ops):
    // swap(pk0, pk2) -> {frag.x, frag.z}; swap(pk1, pk3) -> {frag.y, frag.w}
    #pragma unroll
    for (int kb = 0; kb < 2; ++kb) {
        unsigned fx = pk_[4*kb+0], fz = pk_[4*kb+2];
        unsigned fy = pk_[4*kb+1], fw = pk_[4*kb+3];
        plswap(fx, fz);
        plswap(fy, fw);
        u32x4 wv;
        wv.x = fx; wv.y = fy; wv.z = fz; wv.w = fw;
        short8 pfrag = __builtin_bit_cast(short8, wv);
        __builtin_amdgcn_s_setprio(1);
        o0 = __builtin_amdgcn_mfma_f32_32x32x16_bf16(pfrag, vf0[kb], o0, 0, 0, 0);
        o1 = __builtin_amdgcn_mfma_f32_32x32x16_bf16(pfrag, vf1[kb], o1, 0, 0, 0);
        __builtin_amdgcn_s_setprio(0);
    }
}

__global__ __launch_bounds__(256) void flash_attn(
    const unsigned short* __restrict__ q,
    const unsigned short* __restrict__ k,
    const unsigned short* __restrict__ vt,
    unsigned short* __restrict__ y)
{
    __shared__ float oLDS[2][8][64][4];   // pair, chunk, lane, 4 f32 = 16 KB
    __shared__ float mlLDS[2][2][64];     // pair, {m,l}, lane = 1 KB

    int tid = threadIdx.x, lane = tid & 63, wid = tid >> 6;
    int l31 = lane & 31, hi = lane >> 5;
    int pair = wid >> 1, split = wid & 1;
    int bid = blockIdx.x;

    int qblk = 63 - (bid >> 4);                              // heavy first
    int bh   = (bid & 7)*4 + ((bid >> 3) & 1)*2 + pair;      // head-clustered per XCD

    const unsigned short* qp = q  + ((size_t)bh*T_ + qblk*32) * D_;
    const unsigned short* kp = k  + (size_t)bh*T_*D_;
    const unsigned short* vp = vt + (size_t)bh*D_*T_;

    short8 qf[4];
    #pragma unroll
    for (int dk = 0; dk < 4; ++dk)
        qf[dk] = *reinterpret_cast<const short8*>(qp + (size_t)l31*D_ + dk*16 + hi*8);

    f32x16 o0 = {}, o1 = {};
    float m_ = -1e30f, l_ = 0.f;

    int nt = qblk + 1;
    int half = (nt + 1) >> 1;
    int t0 = split ? half : 0;
    int t1 = split ? nt : half;

    if (t0 < t1) {
        short8 kfA[4], kfB[4];
        const unsigned short* kr = kp + (size_t)(t0*32 + l31) * D_ + hi*8;
        kfA[0] = *reinterpret_cast<const short8*>(kr);
        kfA[1] = *reinterpret_cast<const short8*>(kr + 16);
        kfA[2] = *reinterpret_cast<const short8*>(kr + 32);
        kfA[3] = *reinterpret_cast<const short8*>(kr + 48);

        int ti = t0;
        while (ti + 2 <= t1) {
            attn_tile(ti*32, ti == nt-1, l31, hi, kp, vp, qf, kfA, kfB, o0, o1, m_, l_); ++ti;
            attn_tile(ti*32, ti == nt-1, l31, hi, kp, vp, qf, kfB, kfA, o0, o1, m_, l_); ++ti;
        }
        if (ti < t1) {
            attn_tile(ti*32, ti == nt-1, l31, hi, kp, vp, qf, kfA, kfB, o0, o1, m_, l_); ++ti;
        }
    }

    // ---- merge the two KV-splits via LDS ----
    if (!split) {
        #pragma unroll
        for (int c = 0; c < 4; ++c) {
            float4 v0 = make_float4(o0[4*c], o0[4*c+1], o0[4*c+2], o0[4*c+3]);
            float4 v1 = make_float4(o1[4*c], o1[4*c+1], o1[4*c+2], o1[4*c+3]);
            *reinterpret_cast<float4*>(&oLDS[pair][c][lane][0])   = v0;
            *reinterpret_cast<float4*>(&oLDS[pair][4+c][lane][0]) = v1;
        }
        mlLDS[pair][0][lane] = m_;
        mlLDS[pair][1][lane] = l_;
    }
    __syncthreads();
    if (split) {
        float mA = mlLDS[pair][0][lane];
        float lA = mlLDS[pair][1][lane];
        float mN = fmaxf(mA, m_);
        float aA = exp2f(mA - mN);
        float aB = exp2f(m_ - mN);
        float lN = lA*aA + l_*aB;
        float inv = 1.0f / lN;
        float cA = aA * inv, cB = aB * inv;

        float vals0[16], vals1[16];
        #pragma unroll
        for (int c = 0; c < 4; ++c) {
            *reinterpret_cast<float4*>(&vals0[4*c]) = *reinterpret_cast<float4*>(&oLDS[pair][c][lane][0]);
            *reinterpret_cast<float4*>(&vals1[4*c]) = *reinterpret_cast<float4*>(&oLDS[pair][4+c][lane][0]);
        }

        int b = bh >> 4, h = bh & 15;
        #pragma unroll
        for (int r = 0; r < 16; ++r) {
            int row = (r&3) + 8*(r>>2) + 4*hi;
            float cAr = __shfl(cA, row);
            float cBr = __shfl(cB, row);
            int trow = qblk*32 + row;
            size_t base = ((size_t)(b*T_ + trow))*C_ + h*64;
            y[base + l31]      = f2bf(vals0[r]*cAr + o0[r]*cBr);
            y[base + 32 + l31] = f2bf(vals1[r]*cAr + o1[r]*cBr);
        }
    }
}

extern "C" void kernel_launch(void* const* d_in, const int* in_sizes, int n_in,
                              void* d_out, int out_size, void* d_ws, size_t ws_size,
                              hipStream_t stream) {
    const float* x  = (const float*)d_in[0];
    const float* Wk = (const float*)d_in[1];
    const float* bk = (const float*)d_in[2];
    const float* Wq = (const float*)d_in[3];
    const float* bq = (const float*)d_in[4];
    const float* Wv = (const float*)d_in[5];
    const float* bv = (const float*)d_in[6];
    const float* Wo = (const float*)d_in[7];
    const float* bo = (const float*)d_in[8];
    float* out = (float*)d_out;

    char* ws = (char*)d_ws;
    unsigned short* xb  = (unsigned short*)(ws);                    // 8MB
    unsigned short* wkb = (unsigned short*)(ws + ((size_t)8  << 20));
    unsigned short* wqb = (unsigned short*)(ws + ((size_t)10 << 20));
    unsigned short* wvb = (unsigned short*)(ws + ((size_t)12 << 20));
    unsigned short* wob = (unsigned short*)(ws + ((size_t)14 << 20));
    unsigned short* qb  = (unsigned short*)(ws + ((size_t)16 << 20)); // [B,H,T,D]
    unsigned short* kb  = (unsigned short*)(ws + ((size_t)24 << 20)); // [B,H,T,D]
    unsigned short* vtb = (unsigned short*)(ws + ((size_t)32 << 20)); // [B,H,D,T]
    unsigned short* yb  = (unsigned short*)(ws + ((size_t)40 << 20)); // [B*T,C]

    const int nx = B_*T_*C_;   // 4M
    const int nw = C_*C_;      // 1M

    cvt_bf16<<<dim3(nx/4/256), dim3(256), 0, stream>>>(x, xb, nx);
    cvt_bf16_w4<<<dim3(nw/4/256, 4), dim3(256), 0, stream>>>(
        Wk, Wq, Wv, Wo, wkb, wqb, wvb, wob, nw);

    gemm_qkv<<<dim3(768), dim3(256), 0, stream>>>(xb, wkb, wqb, wvb, bk, bq, bv, kb, qb, vtb);

    flash_attn<<<dim3(1024), dim3(256), 0, stream>>>(qb, kb, vtb, yb);

    gemm_out<<<dim3(256), dim3(256), 0, stream>>>(yb, wob, bo, out);
}

// Round 5
// 143.495 us; speedup vs baseline: 2.1319x; 1.0333x over previous
//
#include <hip/hip_runtime.h>
#include <hip/hip_bf16.h>
#include <stdint.h>
#include <stddef.h>

#define B_ 2
#define T_ 2048
#define C_ 1024
#define H_ 16
#define D_ 64
#define M_ (B_*T_)   // 4096

typedef __attribute__((ext_vector_type(8))) short short8;
typedef __attribute__((ext_vector_type(4))) float f32x4;
typedef __attribute__((ext_vector_type(16))) float f32x16;
typedef __attribute__((ext_vector_type(4))) unsigned int u32x4;

__device__ __forceinline__ unsigned short f2bf(float f) {
    unsigned u = __float_as_uint(f);
    unsigned r = 0x7FFFu + ((u >> 16) & 1u);
    return (unsigned short)((u + r) >> 16);
}

__device__ __forceinline__ unsigned cvtpk_bf16(float lo, float hi) {
    unsigned r;
    asm("v_cvt_pk_bf16_f32 %0, %1, %2" : "=v"(r) : "v"(lo), "v"(hi));
    return r;
}

// v_permlane32_swap_b32: a = [a_lo | b_lo], b = [a_hi | b_hi]
__device__ __forceinline__ void plswap(unsigned &a, unsigned &b) {
    asm("v_permlane32_swap_b32 %0, %1" : "+v"(a), "+v"(b));
}

__device__ __forceinline__ float xhalf_max(float v) {
    float a = v, b = v;
    asm("" : "+v"(b));
    asm("v_permlane32_swap_b32 %0, %1" : "+v"(a), "+v"(b));
    return fmaxf(a, b);
}
__device__ __forceinline__ float xhalf_sum(float v) {
    float a = v, b = v;
    asm("" : "+v"(b));
    asm("v_permlane32_swap_b32 %0, %1" : "+v"(a), "+v"(b));
    return a + b;
}

__device__ __forceinline__ void gload16(const void* g, void* l) {
    __builtin_amdgcn_global_load_lds(
        (__attribute__((address_space(1))) void*)g,
        (__attribute__((address_space(3))) void*)l,
        16, 0, 0);
}

// ---------------- fp32 -> bf16 conversion ----------------
__global__ void cvt_bf16(const float* __restrict__ in,
                         unsigned short* __restrict__ out, int n) {
    int idx = (blockIdx.x * blockDim.x + threadIdx.x) * 4;
    if (idx >= n) return;
    float4 v = *reinterpret_cast<const float4*>(in + idx);
    ushort4 o;
    o.x = f2bf(v.x); o.y = f2bf(v.y); o.z = f2bf(v.z); o.w = f2bf(v.w);
    *reinterpret_cast<ushort4*>(out + idx) = o;
}

__global__ void cvt_bf16_w4(const float* __restrict__ a, const float* __restrict__ b,
                            const float* __restrict__ c, const float* __restrict__ d,
                            unsigned short* __restrict__ oa, unsigned short* __restrict__ ob,
                            unsigned short* __restrict__ oc, unsigned short* __restrict__ od,
                            int n) {
    int idx = (blockIdx.x * blockDim.x + threadIdx.x) * 4;
    if (idx >= n) return;
    const float* in = (blockIdx.y == 0) ? a : (blockIdx.y == 1) ? b : (blockIdx.y == 2) ? c : d;
    unsigned short* out = (blockIdx.y == 0) ? oa : (blockIdx.y == 1) ? ob : (blockIdx.y == 2) ? oc : od;
    float4 v = *reinterpret_cast<const float4*>(in + idx);
    ushort4 o;
    o.x = f2bf(v.x); o.y = f2bf(v.y); o.z = f2bf(v.z); o.w = f2bf(v.w);
    *reinterpret_cast<ushort4*>(out + idx) = o;
}

// ---------------- fused QKV projection GEMM ----------------
// which 0 -> K [B,H,T,D], which 1 -> Q*scale [B,H,T,D], which 2 -> V^T [B,H,D,T]
__global__ __launch_bounds__(256) void gemm_qkv(
    const unsigned short* __restrict__ A,
    const unsigned short* __restrict__ W0,
    const unsigned short* __restrict__ W1,
    const unsigned short* __restrict__ W2,
    const float* __restrict__ b0,
    const float* __restrict__ b1,
    const float* __restrict__ b2,
    unsigned short* __restrict__ o0,   // k
    unsigned short* __restrict__ o1,   // q (pre-scaled by LOG2E/32)
    unsigned short* __restrict__ o2)   // vt
{
    __shared__ unsigned short As[128*32];
    __shared__ unsigned short Bs[128*32];
    int which = blockIdx.x >> 8;
    int bx = blockIdx.x & 255;
    int bm = bx >> 3, bn = bx & 7;
    const unsigned short* W = (which==0) ? W0 : ((which==1) ? W1 : W2);
    const float* bias = (which==0) ? b0 : ((which==1) ? b1 : b2);

    int tid = threadIdx.x;
    int lane = tid & 63;
    int fr = lane & 15, fq = lane >> 4;
    int wid = tid >> 6;
    int wr = wid >> 1, wc = wid & 1;

    int srow = tid >> 2;            // 0..63
    int scol = (tid & 3) << 3;      // 0,8,16,24
    const unsigned short* Ab = A + (size_t)(bm*128 + srow) * C_ + scol;
    const unsigned short* Wb = W + (size_t)(bn*128 + srow) * C_ + scol;

    f32x4 acc[4][4] = {};

    for (int kt = 0; kt < C_/32; ++kt) {
        int ko = kt*32;
        gload16(Ab + ko,            &As[tid*8]);
        gload16(Ab + 64*C_ + ko,    &As[2048 + tid*8]);
        gload16(Wb + ko,            &Bs[tid*8]);
        gload16(Wb + 64*C_ + ko,    &Bs[2048 + tid*8]);
        __syncthreads();
        short8 af[4], bfr[4];
        #pragma unroll
        for (int i = 0; i < 4; ++i) {
            af[i]  = *reinterpret_cast<const short8*>(&As[(wr*64 + i*16 + fr)*32 + fq*8]);
            bfr[i] = *reinterpret_cast<const short8*>(&Bs[(wc*64 + i*16 + fr)*32 + fq*8]);
        }
        #pragma unroll
        for (int i = 0; i < 4; ++i)
            #pragma unroll
            for (int j = 0; j < 4; ++j)
                acc[i][j] = __builtin_amdgcn_mfma_f32_16x16x32_bf16(af[i], bfr[j], acc[i][j], 0, 0, 0);
        __syncthreads();
    }

    // Q: fold 1/sqrt(C)=1/32 AND log2(e) so QK^T lands in log2 domain
    float sc = (which == 1) ? 0.045084220f : 1.0f;
    int mbase = bm*128 + wr*64;
    int nbase = bn*128 + wc*64;
    #pragma unroll
    for (int j = 0; j < 4; ++j) {
        int col = nbase + j*16 + fr;
        float bv = bias[col];
        int h = col >> 6, d = col & 63;
        #pragma unroll
        for (int i = 0; i < 4; ++i) {
            int r0 = mbase + i*16 + fq*4;
            #pragma unroll
            for (int r = 0; r < 4; ++r) {
                float v = (acc[i][j][r] + bv) * sc;
                int m = r0 + r;
                int b = m >> 11, t = m & (T_-1);
                unsigned short hv = f2bf(v);
                if (which == 2)
                    o2[((size_t)(b*H_ + h)*D_ + d)*T_ + t] = hv;
                else {
                    unsigned short* o = (which==0) ? o0 : o1;
                    o[((size_t)(b*H_ + h)*T_ + t)*D_ + d] = hv;
                }
            }
        }
    }
}

// ---------------- output projection GEMM ----------------
__global__ __launch_bounds__(256) void gemm_out(
    const unsigned short* __restrict__ A,   // y bf16 [M_][C_]
    const unsigned short* __restrict__ W,   // Wo bf16 [C_][C_]
    const float* __restrict__ bias,
    float* __restrict__ out)
{
    __shared__ unsigned short As[128*32];
    __shared__ unsigned short Bs[128*32];
    int bx = blockIdx.x;
    int bm = bx >> 3, bn = bx & 7;

    int tid = threadIdx.x;
    int lane = tid & 63;
    int fr = lane & 15, fq = lane >> 4;
    int wid = tid >> 6;
    int wr = wid >> 1, wc = wid & 1;

    int srow = tid >> 2;
    int scol = (tid & 3) << 3;
    const unsigned short* Ab = A + (size_t)(bm*128 + srow) * C_ + scol;
    const unsigned short* Wb = W + (size_t)(bn*128 + srow) * C_ + scol;

    f32x4 acc[4][4] = {};

    for (int kt = 0; kt < C_/32; ++kt) {
        int ko = kt*32;
        gload16(Ab + ko,            &As[tid*8]);
        gload16(Ab + 64*C_ + ko,    &As[2048 + tid*8]);
        gload16(Wb + ko,            &Bs[tid*8]);
        gload16(Wb + 64*C_ + ko,    &Bs[2048 + tid*8]);
        __syncthreads();
        short8 af[4], bfr[4];
        #pragma unroll
        for (int i = 0; i < 4; ++i) {
            af[i]  = *reinterpret_cast<const short8*>(&As[(wr*64 + i*16 + fr)*32 + fq*8]);
            bfr[i] = *reinterpret_cast<const short8*>(&Bs[(wc*64 + i*16 + fr)*32 + fq*8]);
        }
        #pragma unroll
        for (int i = 0; i < 4; ++i)
            #pragma unroll
            for (int j = 0; j < 4; ++j)
                acc[i][j] = __builtin_amdgcn_mfma_f32_16x16x32_bf16(af[i], bfr[j], acc[i][j], 0, 0, 0);
        __syncthreads();
    }

    int mbase = bm*128 + wr*64;
    int nbase = bn*128 + wc*64;
    #pragma unroll
    for (int j = 0; j < 4; ++j) {
        int col = nbase + j*16 + fr;
        float bv = bias[col];
        #pragma unroll
        for (int i = 0; i < 4; ++i) {
            int r0 = mbase + i*16 + fq*4;
            #pragma unroll
            for (int r = 0; r < 4; ++r)
                out[(size_t)(r0 + r)*C_ + col] = acc[i][j][r] + bv;
        }
    }
}

// ---------------- flash attention (causal), swapped-QK^T 32x32 ----------------
// Uniform-work version: block = (bh, qblk pair {j, 63-j}); each phase 4-way KV
// split across the block's 4 waves; partials merged via LDS.
__device__ __forceinline__ void attn_tile(
    int kv0, bool isLast, int l31, int hi,
    const unsigned short* __restrict__ kp,
    const unsigned short* __restrict__ vp,
    const short8 (&qf)[4], const short8 (&kcur)[4], short8 (&knxt)[4],
    f32x16& o0, f32x16& o1, float& m_, float& l_)
{
    // prefetch next tile's K fragments (flies during softmax+PV)
    const unsigned short* kr = kp + (size_t)(kv0 + 32 + l31) * D_ + hi*8;
    knxt[0] = *reinterpret_cast<const short8*>(kr);
    knxt[1] = *reinterpret_cast<const short8*>(kr + 16);
    knxt[2] = *reinterpret_cast<const short8*>(kr + 32);
    knxt[3] = *reinterpret_cast<const short8*>(kr + 48);

    // QK^T (swapped: A=K, B=Q): a0 col = q row (l31), row = kv_local
    f32x16 a0 = {};
    __builtin_amdgcn_s_setprio(1);
    a0 = __builtin_amdgcn_mfma_f32_32x32x16_bf16(kcur[0], qf[0], a0, 0, 0, 0);
    a0 = __builtin_amdgcn_mfma_f32_32x32x16_bf16(kcur[1], qf[1], a0, 0, 0, 0);
    a0 = __builtin_amdgcn_mfma_f32_32x32x16_bf16(kcur[2], qf[2], a0, 0, 0, 0);
    a0 = __builtin_amdgcn_mfma_f32_32x32x16_bf16(kcur[3], qf[3], a0, 0, 0, 0);
    __builtin_amdgcn_s_setprio(0);

    // V fragment loads (issued early; consumed after softmax)
    short8 vf0[2], vf1[2];
    const unsigned short* vr0 = vp + (size_t)l31*T_ + kv0 + hi*8;
    const unsigned short* vr1 = vp + (size_t)(32 + l31)*T_ + kv0 + hi*8;
    vf0[0] = *reinterpret_cast<const short8*>(vr0);
    vf0[1] = *reinterpret_cast<const short8*>(vr0 + 16);
    vf1[0] = *reinterpret_cast<const short8*>(vr1);
    vf1[1] = *reinterpret_cast<const short8*>(vr1 + 16);

    // causal mask: only the diagonal tile needs it
    if (isLast) {
        #pragma unroll
        for (int r = 0; r < 16; ++r) {
            int kvl = (r&3) + 8*(r>>2) + 4*hi;
            if (kvl > l31) a0[r] = -1e30f;
        }
    }

    // row max: pairwise tree + cross-half swap
    float x0 = fmaxf(a0[0], a0[1]),   x1 = fmaxf(a0[2], a0[3]);
    float x2 = fmaxf(a0[4], a0[5]),   x3 = fmaxf(a0[6], a0[7]);
    float x4 = fmaxf(a0[8], a0[9]),   x5 = fmaxf(a0[10], a0[11]);
    float x6 = fmaxf(a0[12], a0[13]), x7 = fmaxf(a0[14], a0[15]);
    float y0 = fmaxf(x0, x1), y1 = fmaxf(x2, x3), y2 = fmaxf(x4, x5), y3 = fmaxf(x6, x7);
    float pm = fmaxf(fmaxf(y0, y1), fmaxf(y2, y3));
    pm = xhalf_max(pm);

    // defer-max (T13)
    if (!__all(pm - m_ <= 8.0f)) {
        float mn = fmaxf(m_, pm);
        float alpha = exp2f(m_ - mn);
        l_ *= alpha;
        m_ = mn;
        #pragma unroll
        for (int r = 0; r < 16; ++r) {
            int row = (r&3) + 8*(r>>2) + 4*hi;
            float ar = __shfl(alpha, row);
            o0[r] *= ar;
            o1[r] *= ar;
        }
    }

    // P = exp2(s - m); row sum via pairwise tree + cross-half swap
    #pragma unroll
    for (int r = 0; r < 16; ++r)
        a0[r] = exp2f(a0[r] - m_);
    float s0 = a0[0]+a0[1],  s1 = a0[2]+a0[3],  s2 = a0[4]+a0[5],   s3 = a0[6]+a0[7];
    float s4 = a0[8]+a0[9],  s5 = a0[10]+a0[11], s6 = a0[12]+a0[13], s7 = a0[14]+a0[15];
    float u0 = s0+s1, u1 = s2+s3, u2 = s4+s5, u3 = s6+s7;
    float rs = (u0+u1) + (u2+u3);
    rs = xhalf_sum(rs);
    l_ += rs;

    // pack P to bf16 pairs
    unsigned pk_[8];
    #pragma unroll
    for (int jj = 0; jj < 8; ++jj)
        pk_[jj] = cvtpk_bf16(a0[2*jj], a0[2*jj+1]);

    // PV: A-frag redistribution via permlane32_swap
    #pragma unroll
    for (int kb = 0; kb < 2; ++kb) {
        unsigned fx = pk_[4*kb+0], fz = pk_[4*kb+2];
        unsigned fy = pk_[4*kb+1], fw = pk_[4*kb+3];
        plswap(fx, fz);
        plswap(fy, fw);
        u32x4 wv;
        wv.x = fx; wv.y = fy; wv.z = fz; wv.w = fw;
        short8 pfrag = __builtin_bit_cast(short8, wv);
        __builtin_amdgcn_s_setprio(1);
        o0 = __builtin_amdgcn_mfma_f32_32x32x16_bf16(pfrag, vf0[kb], o0, 0, 0, 0);
        o1 = __builtin_amdgcn_mfma_f32_32x32x16_bf16(pfrag, vf1[kb], o1, 0, 0, 0);
        __builtin_amdgcn_s_setprio(0);
    }
}

__global__ __launch_bounds__(256) void flash_attn(
    const unsigned short* __restrict__ q,
    const unsigned short* __restrict__ k,
    const unsigned short* __restrict__ vt,
    unsigned short* __restrict__ y)
{
    __shared__ float oP[4][32][68];   // split, q-row, d (pad 64->68) = 34 KB
    __shared__ float mP[4][32];
    __shared__ float lP[4][32];

    int tid = threadIdx.x, lane = tid & 63, s = tid >> 6;   // s = KV split 0..3
    int l31 = lane & 31, hi = lane >> 5;
    int bid = blockIdx.x;

    int xcd = bid & 7;
    int idx = bid >> 3;               // 0..127
    int bh  = xcd*4 + (idx & 3);      // 4 heads per XCD for L2 locality
    int j   = idx >> 2;               // 0..31

    const unsigned short* kp = k  + (size_t)bh*T_*D_;
    const unsigned short* vp = vt + (size_t)bh*D_*T_;
    int b = bh >> 4, h = bh & 15;

    #pragma unroll
    for (int ph = 0; ph < 2; ++ph) {
        int qblk = ph ? (63 - j) : j;
        const unsigned short* qp = q + ((size_t)bh*T_ + qblk*32) * D_;

        short8 qf[4];
        #pragma unroll
        for (int dk = 0; dk < 4; ++dk)
            qf[dk] = *reinterpret_cast<const short8*>(qp + (size_t)l31*D_ + dk*16 + hi*8);

        f32x16 o0 = {}, o1 = {};
        float m_ = -1e30f, l_ = 0.f;

        int nt = qblk + 1;
        int chunk = (nt + 3) >> 2;
        int t0 = s * chunk; if (t0 > nt) t0 = nt;
        int t1 = t0 + chunk; if (t1 > nt) t1 = nt;

        if (t0 < t1) {
            short8 kfA[4], kfB[4];
            const unsigned short* kr = kp + (size_t)(t0*32 + l31) * D_ + hi*8;
            kfA[0] = *reinterpret_cast<const short8*>(kr);
            kfA[1] = *reinterpret_cast<const short8*>(kr + 16);
            kfA[2] = *reinterpret_cast<const short8*>(kr + 32);
            kfA[3] = *reinterpret_cast<const short8*>(kr + 48);

            int ti = t0;
            while (ti + 2 <= t1) {
                attn_tile(ti*32, ti == nt-1, l31, hi, kp, vp, qf, kfA, kfB, o0, o1, m_, l_); ++ti;
                attn_tile(ti*32, ti == nt-1, l31, hi, kp, vp, qf, kfB, kfA, o0, o1, m_, l_); ++ti;
            }
            if (ti < t1) {
                attn_tile(ti*32, ti == nt-1, l31, hi, kp, vp, qf, kfA, kfB, o0, o1, m_, l_); ++ti;
            }
        }

        // ---- store partials ----
        #pragma unroll
        for (int r = 0; r < 16; ++r) {
            int crow = (r&3) + 8*(r>>2) + 4*hi;
            oP[s][crow][l31]      = o0[r];
            oP[s][crow][32 + l31] = o1[r];
        }
        if (!hi) { mP[s][l31] = m_; lP[s][l31] = l_; }
        __syncthreads();

        // ---- 4-way merge + y write ----
        {
            int qr = tid >> 3;        // 0..31
            int dc = tid & 7;         // 0..7 (8 d each)
            float m0 = mP[0][qr], m1 = mP[1][qr], m2 = mP[2][qr], m3 = mP[3][qr];
            float ms = fmaxf(fmaxf(m0, m1), fmaxf(m2, m3));
            float a0_ = exp2f(m0 - ms), a1_ = exp2f(m1 - ms);
            float a2_ = exp2f(m2 - ms), a3_ = exp2f(m3 - ms);
            float ls = a0_*lP[0][qr] + a1_*lP[1][qr] + a2_*lP[2][qr] + a3_*lP[3][qr];
            float inv = 1.0f / ls;

            float4 v0a = *reinterpret_cast<const float4*>(&oP[0][qr][dc*8]);
            float4 v0b = *reinterpret_cast<const float4*>(&oP[0][qr][dc*8+4]);
            float4 v1a = *reinterpret_cast<const float4*>(&oP[1][qr][dc*8]);
            float4 v1b = *reinterpret_cast<const float4*>(&oP[1][qr][dc*8+4]);
            float4 v2a = *reinterpret_cast<const float4*>(&oP[2][qr][dc*8]);
            float4 v2b = *reinterpret_cast<const float4*>(&oP[2][qr][dc*8+4]);
            float4 v3a = *reinterpret_cast<const float4*>(&oP[3][qr][dc*8]);
            float4 v3b = *reinterpret_cast<const float4*>(&oP[3][qr][dc*8+4]);

            float va[8];
            va[0] = a0_*v0a.x + a1_*v1a.x + a2_*v2a.x + a3_*v3a.x;
            va[1] = a0_*v0a.y + a1_*v1a.y + a2_*v2a.y + a3_*v3a.y;
            va[2] = a0_*v0a.z + a1_*v1a.z + a2_*v2a.z + a3_*v3a.z;
            va[3] = a0_*v0a.w + a1_*v1a.w + a2_*v2a.w + a3_*v3a.w;
            va[4] = a0_*v0b.x + a1_*v1b.x + a2_*v2b.x + a3_*v3b.x;
            va[5] = a0_*v0b.y + a1_*v1b.y + a2_*v2b.y + a3_*v3b.y;
            va[6] = a0_*v0b.z + a1_*v1b.z + a2_*v2b.z + a3_*v3b.z;
            va[7] = a0_*v0b.w + a1_*v1b.w + a2_*v2b.w + a3_*v3b.w;

            unsigned short yv[8];
            #pragma unroll
            for (int e = 0; e < 8; ++e) yv[e] = f2bf(va[e] * inv);

            int trow = qblk*32 + qr;
            size_t base = ((size_t)(b*T_ + trow))*C_ + h*64 + dc*8;
            *reinterpret_cast<short8*>(y + base) = *reinterpret_cast<short8*>(yv);
        }
        __syncthreads();   // protect LDS reuse by next phase
    }
}

extern "C" void kernel_launch(void* const* d_in, const int* in_sizes, int n_in,
                              void* d_out, int out_size, void* d_ws, size_t ws_size,
                              hipStream_t stream) {
    const float* x  = (const float*)d_in[0];
    const float* Wk = (const float*)d_in[1];
    const float* bk = (const float*)d_in[2];
    const float* Wq = (const float*)d_in[3];
    const float* bq = (const float*)d_in[4];
    const float* Wv = (const float*)d_in[5];
    const float* bv = (const float*)d_in[6];
    const float* Wo = (const float*)d_in[7];
    const float* bo = (const float*)d_in[8];
    float* out = (float*)d_out;

    char* ws = (char*)d_ws;
    unsigned short* xb  = (unsigned short*)(ws);                    // 8MB
    unsigned short* wkb = (unsigned short*)(ws + ((size_t)8  << 20));
    unsigned short* wqb = (unsigned short*)(ws + ((size_t)10 << 20));
    unsigned short* wvb = (unsigned short*)(ws + ((size_t)12 << 20));
    unsigned short* wob = (unsigned short*)(ws + ((size_t)14 << 20));
    unsigned short* qb  = (unsigned short*)(ws + ((size_t)16 << 20)); // [B,H,T,D]
    unsigned short* kb  = (unsigned short*)(ws + ((size_t)24 << 20)); // [B,H,T,D]
    unsigned short* vtb = (unsigned short*)(ws + ((size_t)32 << 20)); // [B,H,D,T]
    unsigned short* yb  = (unsigned short*)(ws + ((size_t)40 << 20)); // [B*T,C]

    const int nx = B_*T_*C_;   // 4M
    const int nw = C_*C_;      // 1M

    cvt_bf16<<<dim3(nx/4/256), dim3(256), 0, stream>>>(x, xb, nx);
    cvt_bf16_w4<<<dim3(nw/4/256, 4), dim3(256), 0, stream>>>(
        Wk, Wq, Wv, Wo, wkb, wqb, wvb, wob, nw);

    gemm_qkv<<<dim3(768), dim3(256), 0, stream>>>(xb, wkb, wqb, wvb, bk, bq, bv, kb, qb, vtb);

    flash_attn<<<dim3(1024), dim3(256), 0, stream>>>(qb, kb, vtb, yb);

    gemm_out<<<dim3(256), dim3(256), 0, stream>>>(yb, wob, bo, out);
}